// Round 1
// baseline (1748.276 us; speedup 1.0000x reference)
//
#include <hip/hip_runtime.h>
#include <cstdint>

// ---- JAX PRNG mode switches -------------------------------------------------
// JPART=1: jax_threefry_partitionable (default True in modern JAX)
// PART_XOR=1: 32-bit draws are o0^o1 (believed); 0: second word o1
#define JPART 1
#define PART_XOR 1

constexpr uint32_t N20   = 1u << 20;   // noise length n = 16*64*32*32
constexpr uint32_t NHALF = 1u << 19;   // 524288
constexpr uint32_t NSPEC = NHALF + 1;  // 524289 rfft bins
constexpr uint32_t SPEC_STRIDE = 524544; // padded per-stream stride (complex elems)

struct Hdr {
  float e_r, e_i, amp_r, amp_i;
  int   phi_r, phi_i;
  float nhe_r, nhe_i;     // -e/2
  float scale_s[4];       // per-stream time-domain scale amp/(sigma*N)
};
struct KeyArgs { uint32_t k[8][2]; }; // [stream(4) * 2 + part(R/I)]

// ---- Threefry2x32-20 (exact JAX cipher) ------------------------------------
__host__ __device__ inline void tf2x32(uint32_t k0, uint32_t k1, uint32_t x0, uint32_t x1,
                                       uint32_t& o0, uint32_t& o1) {
  const uint32_t ks0 = k0, ks1 = k1, ks2 = k0 ^ k1 ^ 0x1BD11BDAu;
  const uint32_t ks[3] = { ks0, ks1, ks2 };
  x0 += ks0; x1 += ks1;
  const int rot[2][4] = { {13,15,26,6}, {17,29,16,24} };
  for (int g = 0; g < 5; ++g) {
    const int* rr = rot[g & 1];
    for (int i = 0; i < 4; ++i) {
      x0 += x1;
      x1 = (x1 << rr[i]) | (x1 >> (32 - rr[i]));
      x1 ^= x0;
    }
    x0 += ks[(g + 1) % 3];
    x1 += ks[(g + 2) % 3] + (uint32_t)(g + 1);
  }
  o0 = x0; o1 = x1;
}

// ---- XLA ErfInv32 polynomial (Giles) ---------------------------------------
__device__ inline float erfinv_xla(float x) {
  float w = -log1pf(-x * x);
  float p;
  if (w < 5.0f) {
    w -= 2.5f;
    p = 2.81022636e-08f;
    p = fmaf(p, w, 3.43273939e-07f);
    p = fmaf(p, w, -3.5233877e-06f);
    p = fmaf(p, w, -4.39150654e-06f);
    p = fmaf(p, w, 0.00021858087f);
    p = fmaf(p, w, -0.00125372503f);
    p = fmaf(p, w, -0.00417768164f);
    p = fmaf(p, w, 0.246640727f);
    p = fmaf(p, w, 1.50140941f);
  } else {
    w = sqrtf(w) - 3.0f;
    p = -0.000200214257f;
    p = fmaf(p, w, 0.000100950558f);
    p = fmaf(p, w, 0.00134934322f);
    p = fmaf(p, w, -0.00367342844f);
    p = fmaf(p, w, 0.00573950773f);
    p = fmaf(p, w, -0.0076224613f);
    p = fmaf(p, w, 0.00943887047f);
    p = fmaf(p, w, 1.00167406f);
    p = fmaf(p, w, 2.83297682f);
  }
  return p * x;
}

__device__ inline float normal_from_bits(uint32_t bits) {
  uint32_t fb = (bits >> 9) | 0x3f800000u;
  float f = __uint_as_float(fb) - 1.0f;          // [0,1)
  const float LO = -0.99999994f;                  // nextafter(-1,0)
  float u = f * 2.0f + LO;                        // (maxval-minval) rounds to 2.0f; f*2 exact
  u = fmaxf(LO, u);
  return 1.41421356f * erfinv_xla(u);
}

__device__ inline float sscale_f(uint32_t k, float nhe) {
  uint32_t kk = k ? k : 1u;
  return powf((float)kk * (1.0f / 1048576.0f), nhe);
}

__device__ inline float2 cmul(float2 a, float2 b) {
  return make_float2(a.x * b.x - a.y * b.y, a.x * b.y + a.y * b.x);
}
__device__ inline float2 wexp(float u) {  // e^{+2*pi*i*u}; u exact rational -> accurate
  float s, c; sincospif(2.0f * u, &s, &c); return make_float2(c, s);
}

// ---- scalars: medians ------------------------------------------------------
__device__ inline float med8_dev(const float* p) {
  float v[8];
  for (int i = 0; i < 8; ++i) v[i] = p[i];
  for (int i = 1; i < 8; ++i) { float key = v[i]; int j = i - 1;
    while (j >= 0 && v[j] > key) { v[j + 1] = v[j]; --j; } v[j + 1] = key; }
  return 0.5f * (v[3] + v[4]);
}

__global__ void k_scalars(Hdr* h, const float* er, const float* ei, const float* ar,
                          const float* ai, const float* pr, const float* pim) {
  if (threadIdx.x || blockIdx.x) return;
  float mer = med8_dev(er), mei = med8_dev(ei);
  h->e_r = mer; h->e_i = mei;
  h->amp_r = med8_dev(ar); h->amp_i = med8_dev(ai);
  h->phi_r = (int)med8_dev(pr);   // astype(int32) truncates toward zero
  h->phi_i = (int)med8_dev(pim);
  h->nhe_r = -0.5f * mer; h->nhe_i = -0.5f * mei;
}

// ---- sigma = 2*sqrt(sum(w*w))/n  (deterministic two-stage reduction) -------
__global__ void k_sumw2(const Hdr* __restrict__ h, float* __restrict__ partials) {
  __shared__ float sr_[256], si_[256];
  const float nher = h->nhe_r, nhei = h->nhe_i;
  float sr = 0.f, si = 0.f;
  for (int j = 0; j < 4; ++j) {
    uint32_t k = (uint32_t)(blockIdx.x * 1024 + j * 256 + threadIdx.x) + 1u; // 1..524288
    float fk = (float)k * (1.0f / 1048576.0f);
    float wr = powf(fk, nher), wi = powf(fk, nhei);
    if (k == NHALF) { wr *= 0.5f; wi *= 0.5f; }   // w[-1] *= (1+n%2)/2
    sr += wr * wr; si += wi * wi;
  }
  sr_[threadIdx.x] = sr; si_[threadIdx.x] = si; __syncthreads();
  for (int off = 128; off > 0; off >>= 1) {
    if ((int)threadIdx.x < off) { sr_[threadIdx.x] += sr_[threadIdx.x + off];
                                  si_[threadIdx.x] += si_[threadIdx.x + off]; }
    __syncthreads();
  }
  if (!threadIdx.x) { partials[blockIdx.x * 2] = sr_[0]; partials[blockIdx.x * 2 + 1] = si_[0]; }
}

__global__ void k_sumw2_fin(Hdr* h, const float* partials) {
  if (threadIdx.x || blockIdx.x) return;
  float Sr = 0.f, Si = 0.f;
  for (int b = 0; b < 512; ++b) { Sr += partials[b * 2]; Si += partials[b * 2 + 1]; }
  float sig_r = 2.0f * sqrtf(Sr) * (1.0f / 1048576.0f);
  float sig_i = 2.0f * sqrtf(Si) * (1.0f / 1048576.0f);
  float s0 = h->amp_r / (sig_r * 1048576.0f);               // nr scale (roll * amp_r, /N /sigma)
  float s1 = (h->amp_i * h->amp_i) / (sig_i * 1048576.0f);  // ni scale (amp_i applied twice)
  h->scale_s[0] = s0; h->scale_s[1] = s1; h->scale_s[2] = s0; h->scale_s[3] = s1;
}

// ---- wsum[c][m1][m2] = sum_oc w[c,oc,m1,m2,:] ------------------------------
__global__ void k_wsum(const float* __restrict__ w1, const float* __restrict__ w2,
                       float2* __restrict__ wsum) {
  int idx = blockIdx.x * 256 + threadIdx.x;     // 0..131071
  int sel = idx >> 16, rem = idx & 65535;
  const float* w = sel ? w2 : w1;
  int c = rem >> 10, m1 = (rem >> 5) & 31, m2 = rem & 31;
  size_t base = (size_t)c * 131072 + (size_t)m1 * 64 + (size_t)m2 * 2;
  float sr = 0.f, si = 0.f;
  for (int oc = 0; oc < 64; ++oc) { sr += w[base + (size_t)oc * 2048]; si += w[base + (size_t)oc * 2048 + 1]; }
  wsum[idx] = make_float2(sr, si);
}

// ---- noise spectra: sr + i*si, shaped by s_scale ---------------------------
__global__ void k_noise_spec(float2* __restrict__ spec, const Hdr* __restrict__ h, KeyArgs ka) {
  const int combo = blockIdx.y;            // s*2 + part
  const int s = combo >> 1, part = combo & 1;
  const float nhe = ((s & 1) == 0) ? h->nhe_r : h->nhe_i;  // streams 0,2: e_r; 1,3: e_i
  const uint32_t K0 = ka.k[combo][0], K1 = ka.k[combo][1];
  float2* sp = spec + (size_t)s * SPEC_STRIDE;
  const int i = blockIdx.x * 256 + threadIdx.x;
#if JPART
  if (i >= (int)NSPEC) return;
  uint32_t o0, o1; tf2x32(K0, K1, 0u, (uint32_t)i, o0, o1);
#if PART_XOR
  uint32_t bits = o0 ^ o1;
#else
  uint32_t bits = o1;
#endif
  float val = normal_from_bits(bits) * sscale_f((uint32_t)i, nhe);
  if (i == 0 || i == (int)NHALF) val = part ? 0.0f : val * 1.41421356f;
  if (part) sp[i].y = val; else sp[i].x = val;
#else
  if (i >= 262145) return;
  uint32_t c1 = (i == 262144) ? 0u : (uint32_t)(i + 262145);
  uint32_t o0, o1; tf2x32(K0, K1, (uint32_t)i, c1, o0, o1);
  {
    uint32_t k = (uint32_t)i;
    float v = normal_from_bits(o0) * sscale_f(k, nhe);
    if (k == 0u) v = part ? 0.0f : v * 1.41421356f;
    if (part) sp[k].y = v; else sp[k].x = v;
  }
  if (i < 262144) {
    uint32_t k = (uint32_t)i + 262145u;
    float v = normal_from_bits(o1) * sscale_f(k, nhe);
    if (k == NHALF) v = part ? 0.0f : v * 1.41421356f;
    if (part) sp[k].y = v; else sp[k].x = v;
  }
#endif
}

// ---- 1024-point DFT (sign +) in LDS, two radix-32 passes -------------------
// out[c+32d] = sum_a W32^{da} [ W1024^{ca} * sum_b in[a+32b] W32^{cb} ]
__device__ inline void fft1024(float2* io, float2* tmp, int t) {
  #pragma unroll
  for (int q = 0; q < 4; ++q) {
    int p = t + (q << 8); int a = p >> 5, c = p & 31;
    float2 wst = wexp((float)c * (1.0f / 32.0f));
    float2 w = wst;
    float2 sv = io[a];                       // b = 0 term (w=1)
    for (int b = 1; b < 32; ++b) {
      float2 v = io[a + (b << 5)];
      sv.x = fmaf(v.x, w.x, sv.x); sv.x = fmaf(-v.y, w.y, sv.x);
      sv.y = fmaf(v.x, w.y, sv.y); sv.y = fmaf(v.y, w.x, sv.y);
      w = cmul(w, wst);
    }
    float2 tw = wexp((float)(c * a) * (1.0f / 1024.0f));
    tmp[(a << 5) + c] = cmul(sv, tw);
  }
  __syncthreads();
  #pragma unroll
  for (int q = 0; q < 4; ++q) {
    int p = t + (q << 8); int d = p >> 5, c = p & 31;
    float2 wst = wexp((float)d * (1.0f / 32.0f));
    float2 w = wst;
    float2 sv = tmp[c];                      // a = 0 term
    for (int a = 1; a < 32; ++a) {
      float2 v = tmp[(a << 5) + c];
      sv.x = fmaf(v.x, w.x, sv.x); sv.x = fmaf(-v.y, w.y, sv.x);
      sv.y = fmaf(v.x, w.y, sv.y); sv.y = fmaf(v.y, w.x, sv.y);
      w = cmul(w, wst);
    }
    io[c + (d << 5)] = sv;
  }
  __syncthreads();
}

// ---- irfft(2^20) stage 1: per k1, FFT over k2 + outer twiddle --------------
__global__ __launch_bounds__(256) void k_fft_s1(const float2* __restrict__ spec,
                                                float2* __restrict__ G) {
  __shared__ float2 io[1024], tmp[1024];
  const int k1 = blockIdx.x, arr = blockIdx.y, t = threadIdx.x;
  const float2* sp = spec + (size_t)arr * SPEC_STRIDE;
  #pragma unroll
  for (int q = 0; q < 4; ++q) {
    int k2 = t + (q << 8);
    uint32_t k = (uint32_t)k1 + ((uint32_t)k2 << 10);
    float2 cv;
    if (k <= NHALF) cv = sp[k];
    else { float2 v = sp[N20 - k]; cv = make_float2(v.x, -v.y); }  // Hermitian ext.
    io[k2] = cv;
  }
  __syncthreads();
  fft1024(io, tmp, t);
  #pragma unroll
  for (int q = 0; q < 4; ++q) {
    int j2 = t + (q << 8);
    float2 tw = wexp((float)(j2 * k1) * (1.0f / 1048576.0f));  // exact: j2*k1 < 2^20
    float2 v = cmul(io[j2], tw);
    G[((size_t)arr << 20) + ((size_t)j2 << 10) + (size_t)k1] = v; // transposed store
  }
}

// ---- stage 2: per j2, FFT over k1; write real part in permuted layout -------
// X[j2 + 1024*j1] stored at noise[(j2<<10) + j1]
__global__ __launch_bounds__(256) void k_fft_s2(const float2* __restrict__ G,
                                                float* __restrict__ noise,
                                                const Hdr* __restrict__ h) {
  __shared__ float2 io[1024], tmp[1024];
  const int j2 = blockIdx.x, arr = blockIdx.y, t = threadIdx.x;
  const float2* gp = G + ((size_t)arr << 20) + ((size_t)j2 << 10);
  #pragma unroll
  for (int q = 0; q < 4; ++q) { int k1 = t + (q << 8); io[k1] = gp[k1]; }
  __syncthreads();
  fft1024(io, tmp, t);
  const float sc = h->scale_s[arr];
  float* np_ = noise + ((size_t)arr << 20) + ((size_t)j2 << 10);
  #pragma unroll
  for (int q = 0; q < 4; ++q) { int j1 = t + (q << 8); np_[j1] = io[j1].x * sc; }
}

// ---- forward: partial rfft2 at kept modes, * wsum, - noise -> OFT ----------
// one block per (b,c) image; OFT[bc][kyp<64][kx<32], kyp>=32 => ky=kyp+192
__global__ __launch_bounds__(256, 3) void k_forward(const float* __restrict__ x,
    const float2* __restrict__ wsum, const float* __restrict__ noise,
    const Hdr* __restrict__ h, float2* __restrict__ oftg) {
  __shared__ float xs[32][257];
  __shared__ float2 X1c[32][33];
  const int bc = blockIdx.x, t = threadIdx.x;
  const int c = bc & 63;
  const int kx1 = t >> 3, yb = (t & 7) << 2;   // phase-1a mapping
  const int kxo = t & 31, kg = t >> 5;         // accumulator ownership

  float2 acc[8];
  #pragma unroll
  for (int r = 0; r < 8; ++r) acc[r] = make_float2(0.f, 0.f);

  float2 wst1 = wexp((float)kx1 * (1.0f / 256.0f)); wst1.y = -wst1.y; // e^{-2pi i kx/256}
  const float* xim = x + ((size_t)bc << 16);

  for (int y0 = 0; y0 < 256; y0 += 32) {
    #pragma unroll
    for (int i = 0; i < 32; ++i) xs[i][t] = xim[(size_t)((y0 + i) << 8) + t];
    __syncthreads();
    // phase 1a: X1c[y][kx] = sum_x xs[y][x] e^{-2pi i kx x/256}
    {
      float2 s0 = make_float2(0.f,0.f), s1 = s0, s2 = s0, s3 = s0;
      float2 w = make_float2(1.f, 0.f);
      for (int xx = 0; xx < 256; ++xx) {
        float a0 = xs[yb + 0][xx], a1 = xs[yb + 1][xx], a2 = xs[yb + 2][xx], a3 = xs[yb + 3][xx];
        s0.x = fmaf(a0, w.x, s0.x); s0.y = fmaf(a0, w.y, s0.y);
        s1.x = fmaf(a1, w.x, s1.x); s1.y = fmaf(a1, w.y, s1.y);
        s2.x = fmaf(a2, w.x, s2.x); s2.y = fmaf(a2, w.y, s2.y);
        s3.x = fmaf(a3, w.x, s3.x); s3.y = fmaf(a3, w.y, s3.y);
        w = cmul(w, wst1);
      }
      X1c[yb + 0][kx1] = s0; X1c[yb + 1][kx1] = s1; X1c[yb + 2][kx1] = s2; X1c[yb + 3][kx1] = s3;
    }
    __syncthreads();
    // phase 1b: acc[kyp][kxo] += sum_y X1c[y][kxo] e^{-2pi i ky (y0+y)/256}
    #pragma unroll
    for (int r = 0; r < 8; ++r) {
      int kyp = (kg << 3) + r;
      int ky = (kyp < 32) ? kyp : kyp + 192;
      float2 w = wexp((float)((ky * y0) & 255) * (1.0f / 256.0f)); w.y = -w.y;
      float2 wst = wexp((float)(ky & 255) * (1.0f / 256.0f)); wst.y = -wst.y;
      float2 a = acc[r];
      for (int yy = 0; yy < 32; ++yy) {
        float2 v = X1c[yy][kxo];
        a.x = fmaf(v.x, w.x, a.x); a.x = fmaf(-v.y, w.y, a.x);
        a.y = fmaf(v.x, w.y, a.y); a.y = fmaf(v.y, w.x, a.y);
        w = cmul(w, wst);
      }
      acc[r] = a;
    }
    __syncthreads();
  }

  const int phir = h->phi_r, phii = h->phi_i;
  #pragma unroll
  for (int r = 0; r < 8; ++r) {
    int kyp = (kg << 3) + r;
    int sel = kyp >> 5;          // 0: rows 0..31 (w1/noiseA), 1: rows 224..255 (w2/noiseB)
    int m1 = kyp & 31;
    float2 wv = wsum[((size_t)sel << 16) + (size_t)(((c << 5) | m1) << 5) + (size_t)kxo];
    float2 v;
    v.x = acc[r].x * wv.x - acc[r].y * wv.y;
    v.y = acc[r].x * wv.y + acc[r].y * wv.x;
    uint32_t p = ((uint32_t)((bc << 5) | m1) << 5) | (uint32_t)kxo; // ((b*64+c)*32+m1)*32+m2
    uint32_t qr = (p - (uint32_t)phir) & (N20 - 1u);
    uint32_t qi = (p - (uint32_t)phii) & (N20 - 1u);
    const float* nr = noise + ((size_t)(sel ? 2 : 0) << 20);
    const float* ni = noise + ((size_t)(sel ? 3 : 1) << 20);
    v.x -= nr[((qr & 1023u) << 10) | (qr >> 10)];   // permuted noise layout lookup
    v.y -= ni[((qi & 1023u) << 10) | (qi >> 10)];
    oftg[((size_t)bc << 11) + (size_t)((kyp << 5) | kxo)] = v;
  }
}

// ---- inverse: sparse irfft2 per image --------------------------------------
__global__ __launch_bounds__(256, 2) void k_inverse(const float2* __restrict__ oftg,
                                                    float* __restrict__ out) {
  __shared__ float2 oft[64][32];
  __shared__ float2 T[256][32];
  const int bc = blockIdx.x, t = threadIdx.x;
  #pragma unroll
  for (int q = 0; q < 8; ++q) {
    int i = (q << 8) + t;
    (&oft[0][0])[i] = oftg[((size_t)bc << 11) + i];
  }
  __syncthreads();
  // phase A: T[y][kx] = sum_{ky in S} oft * e^{+2pi i ky y/256}
  const int kx = t & 31, yg = t >> 5;
  for (int r = 0; r < 32; ++r) {
    int y = (yg << 5) + r;
    float2 wst = wexp((float)y * (1.0f / 256.0f));
    float2 w = make_float2(1.f, 0.f);
    float2 sv = make_float2(0.f, 0.f);
    for (int kyp = 0; kyp < 32; ++kyp) {           // ky = 0..31
      float2 v = oft[kyp][kx];
      sv.x = fmaf(v.x, w.x, sv.x); sv.x = fmaf(-v.y, w.y, sv.x);
      sv.y = fmaf(v.x, w.y, sv.y); sv.y = fmaf(v.y, w.x, sv.y);
      w = cmul(w, wst);
    }
    float2 w2 = wexp((float)((224 * y) & 255) * (1.0f / 256.0f)); // ky = 224..255
    for (int kyp = 32; kyp < 64; ++kyp) {
      float2 v = oft[kyp][kx];
      sv.x = fmaf(v.x, w2.x, sv.x); sv.x = fmaf(-v.y, w2.y, sv.x);
      sv.y = fmaf(v.x, w2.y, sv.y); sv.y = fmaf(v.y, w2.x, sv.y);
      w2 = cmul(w2, wst);
    }
    T[y][kx] = sv;
  }
  __syncthreads();
  // phase B: out[y][x] = (1/65536)*(Re T[y,0] + sum_{k=1}^{31} 2(Re cos - Im sin))
  float wc2[32], wn2[32];
  {
    float2 wst = wexp((float)t * (1.0f / 256.0f));
    float2 w = wst;
    wc2[0] = 1.f; wn2[0] = 0.f;
    #pragma unroll
    for (int k = 1; k < 32; ++k) { wc2[k] = 2.f * w.x; wn2[k] = -2.f * w.y; w = cmul(w, wst); }
  }
  const float sc = 1.0f / 65536.0f;
  float* op = out + ((size_t)bc << 16);
  for (int y = 0; y < 256; ++y) {
    float s = T[y][0].x;                 // irfft discards Im of kx=0 column
    #pragma unroll
    for (int k = 1; k < 32; ++k) {
      float2 v = T[y][k];
      s = fmaf(v.x, wc2[k], s);
      s = fmaf(v.y, wn2[k], s);
    }
    op[(y << 8) + t] = s * sc;
  }
}

// ---- host ------------------------------------------------------------------
extern "C" void kernel_launch(void* const* d_in, const int* in_sizes, int n_in,
                              void* d_out, int out_size, void* d_ws, size_t ws_size,
                              hipStream_t stream) {
  (void)in_sizes; (void)n_in; (void)out_size; (void)ws_size;
  const float* x   = (const float*)d_in[0];
  const float* w1  = (const float*)d_in[1];
  const float* w2  = (const float*)d_in[2];
  const float* er  = (const float*)d_in[3];
  const float* ei  = (const float*)d_in[4];
  const float* ar  = (const float*)d_in[5];
  const float* ai  = (const float*)d_in[6];
  const float* pr  = (const float*)d_in[7];
  const float* pim = (const float*)d_in[8];
  float* out = (float*)d_out;

  char* ws = (char*)d_ws;
  Hdr*    hdr      = (Hdr*)ws;                        // scalars
  float*  partials = (float*)(ws + 0x1000);           // 512*2 floats
  float2* wsum     = (float2*)(ws + 0x10000);         // 1 MB
  float2* spec     = (float2*)(ws + 0x200000);        // 4 spectra, ~16.8 MB
  float2* G        = (float2*)(ws + 0x1400000);       // 32 MB FFT intermediate
  float2* oft      = (float2*)(ws + 0x1400000);       // 16 MB, reuses G (G dead by then)
  float*  noise    = (float*)(ws + 0x3400000);        // 16 MB; total ws use = 68 MB

  // Key tree (pure host arithmetic; deterministic; baked into graph as args)
  auto splitk = [](const uint32_t k[2], uint32_t a[2], uint32_t b[2]) {
#if JPART
    tf2x32(k[0], k[1], 0u, 0u, a[0], a[1]);   // key_j = full output of ctr (0, j)
    tf2x32(k[0], k[1], 0u, 1u, b[0], b[1]);
#else
    uint32_t r0[2], r1[2];
    tf2x32(k[0], k[1], 0u, 2u, r0[0], r0[1]); // pairs (0,2),(1,3); concat-halves layout
    tf2x32(k[0], k[1], 1u, 3u, r1[0], r1[1]);
    a[0] = r0[0]; a[1] = r1[0]; b[0] = r0[1]; b[1] = r1[1];
#endif
  };
  uint32_t root[2] = { 0u, 42u };
  uint32_t kA[2], kB[2], k1A[2], k2A[2], k1B[2], k2B[2];
  splitk(root, kA, kB);
  splitk(kA, k1A, k2A);
  splitk(kB, k1B, k2B);
  KeyArgs ka;
  splitk(k1A, ka.k[0], ka.k[1]);  // stream 0 (nr_A): sr key, si key
  splitk(k2A, ka.k[2], ka.k[3]);  // stream 1 (ni_A)
  splitk(k1B, ka.k[4], ka.k[5]);  // stream 2 (nr_B)
  splitk(k2B, ka.k[6], ka.k[7]);  // stream 3 (ni_B)

  hipLaunchKernelGGL(k_scalars,    dim3(1),        dim3(64),  0, stream, hdr, er, ei, ar, ai, pr, pim);
  hipLaunchKernelGGL(k_sumw2,      dim3(512),      dim3(256), 0, stream, hdr, partials);
  hipLaunchKernelGGL(k_sumw2_fin,  dim3(1),        dim3(64),  0, stream, hdr, partials);
  hipLaunchKernelGGL(k_wsum,       dim3(512),      dim3(256), 0, stream, w1, w2, wsum);
  hipLaunchKernelGGL(k_noise_spec, dim3(2049, 8),  dim3(256), 0, stream, spec, hdr, ka);
  hipLaunchKernelGGL(k_fft_s1,     dim3(1024, 4),  dim3(256), 0, stream, spec, G);
  hipLaunchKernelGGL(k_fft_s2,     dim3(1024, 4),  dim3(256), 0, stream, G, noise, hdr);
  hipLaunchKernelGGL(k_forward,    dim3(1024),     dim3(256), 0, stream, x, wsum, noise, hdr, oft);
  hipLaunchKernelGGL(k_inverse,    dim3(1024),     dim3(256), 0, stream, oft, out);
}

// Round 3
// 912.643 us; speedup vs baseline: 1.9156x; 1.9156x over previous
//
#include <hip/hip_runtime.h>
#include <cstdint>

// ---- JAX PRNG mode switches -------------------------------------------------
#define JPART 1
#define PART_XOR 1

constexpr uint32_t N20   = 1u << 20;
constexpr uint32_t NHALF = 1u << 19;
constexpr uint32_t NSPEC = NHALF + 1;
constexpr uint32_t SPEC_STRIDE = 524544;

struct Hdr {
  float e_r, e_i, amp_r, amp_i;
  int   phi_r, phi_i;
  float nhe_r, nhe_i;
  float scale_s[4];
};
struct KeyArgs { uint32_t k[8][2]; };

typedef __attribute__((ext_vector_type(8))) short short8;
typedef __attribute__((ext_vector_type(16))) float f32x16;

__device__ inline f32x16 zero16() {
  f32x16 v;
  #pragma unroll
  for (int i = 0; i < 16; ++i) v[i] = 0.f;
  return v;
}

__device__ inline unsigned short f2bf(float f) {
  uint32_t u = __float_as_uint(f);
  return (unsigned short)((u + 0x7fffu + ((u >> 16) & 1u)) >> 16);
}

// ---- Threefry2x32-20 (exact JAX cipher) ------------------------------------
__host__ __device__ inline void tf2x32(uint32_t k0, uint32_t k1, uint32_t x0, uint32_t x1,
                                       uint32_t& o0, uint32_t& o1) {
  const uint32_t ks0 = k0, ks1 = k1, ks2 = k0 ^ k1 ^ 0x1BD11BDAu;
  const uint32_t ks[3] = { ks0, ks1, ks2 };
  x0 += ks0; x1 += ks1;
  const int rot[2][4] = { {13,15,26,6}, {17,29,16,24} };
  for (int g = 0; g < 5; ++g) {
    const int* rr = rot[g & 1];
    for (int i = 0; i < 4; ++i) {
      x0 += x1;
      x1 = (x1 << rr[i]) | (x1 >> (32 - rr[i]));
      x1 ^= x0;
    }
    x0 += ks[(g + 1) % 3];
    x1 += ks[(g + 2) % 3] + (uint32_t)(g + 1);
  }
  o0 = x0; o1 = x1;
}

// ---- XLA ErfInv32 polynomial ------------------------------------------------
__device__ inline float erfinv_xla(float x) {
  float w = -log1pf(-x * x);
  float p;
  if (w < 5.0f) {
    w -= 2.5f;
    p = 2.81022636e-08f;
    p = fmaf(p, w, 3.43273939e-07f);
    p = fmaf(p, w, -3.5233877e-06f);
    p = fmaf(p, w, -4.39150654e-06f);
    p = fmaf(p, w, 0.00021858087f);
    p = fmaf(p, w, -0.00125372503f);
    p = fmaf(p, w, -0.00417768164f);
    p = fmaf(p, w, 0.246640727f);
    p = fmaf(p, w, 1.50140941f);
  } else {
    w = sqrtf(w) - 3.0f;
    p = -0.000200214257f;
    p = fmaf(p, w, 0.000100950558f);
    p = fmaf(p, w, 0.00134934322f);
    p = fmaf(p, w, -0.00367342844f);
    p = fmaf(p, w, 0.00573950773f);
    p = fmaf(p, w, -0.0076224613f);
    p = fmaf(p, w, 0.00943887047f);
    p = fmaf(p, w, 1.00167406f);
    p = fmaf(p, w, 2.83297682f);
  }
  return p * x;
}

__device__ inline float normal_from_bits(uint32_t bits) {
  uint32_t fb = (bits >> 9) | 0x3f800000u;
  float f = __uint_as_float(fb) - 1.0f;
  const float LO = -0.99999994f;
  float u = f * 2.0f + LO;
  u = fmaxf(LO, u);
  return 1.41421356f * erfinv_xla(u);
}

__device__ inline float sscale_f(uint32_t k, float nhe) {
  uint32_t kk = k ? k : 1u;
  return powf((float)kk * (1.0f / 1048576.0f), nhe);
}

__device__ inline float2 cmul(float2 a, float2 b) {
  return make_float2(a.x * b.x - a.y * b.y, a.x * b.y + a.y * b.x);
}
__device__ inline float2 wexp(float u) {
  float s, c; sincospif(2.0f * u, &s, &c); return make_float2(c, s);
}

// ---- scalars ----------------------------------------------------------------
__device__ inline float med8_dev(const float* p) {
  float v[8];
  for (int i = 0; i < 8; ++i) v[i] = p[i];
  for (int i = 1; i < 8; ++i) { float key = v[i]; int j = i - 1;
    while (j >= 0 && v[j] > key) { v[j + 1] = v[j]; --j; } v[j + 1] = key; }
  return 0.5f * (v[3] + v[4]);
}

__global__ void k_scalars(Hdr* h, const float* er, const float* ei, const float* ar,
                          const float* ai, const float* pr, const float* pim) {
  if (threadIdx.x || blockIdx.x) return;
  float mer = med8_dev(er), mei = med8_dev(ei);
  h->e_r = mer; h->e_i = mei;
  h->amp_r = med8_dev(ar); h->amp_i = med8_dev(ai);
  h->phi_r = (int)med8_dev(pr);
  h->phi_i = (int)med8_dev(pim);
  h->nhe_r = -0.5f * mer; h->nhe_i = -0.5f * mei;
}

__global__ void k_sumw2(const Hdr* __restrict__ h, float* __restrict__ partials) {
  __shared__ float sr_[256], si_[256];
  const float nher = h->nhe_r, nhei = h->nhe_i;
  float sr = 0.f, si = 0.f;
  for (int j = 0; j < 4; ++j) {
    uint32_t k = (uint32_t)(blockIdx.x * 1024 + j * 256 + threadIdx.x) + 1u;
    float fk = (float)k * (1.0f / 1048576.0f);
    float wr = powf(fk, nher), wi = powf(fk, nhei);
    if (k == NHALF) { wr *= 0.5f; wi *= 0.5f; }
    sr += wr * wr; si += wi * wi;
  }
  sr_[threadIdx.x] = sr; si_[threadIdx.x] = si; __syncthreads();
  for (int off = 128; off > 0; off >>= 1) {
    if ((int)threadIdx.x < off) { sr_[threadIdx.x] += sr_[threadIdx.x + off];
                                  si_[threadIdx.x] += si_[threadIdx.x + off]; }
    __syncthreads();
  }
  if (!threadIdx.x) { partials[blockIdx.x * 2] = sr_[0]; partials[blockIdx.x * 2 + 1] = si_[0]; }
}

__global__ void k_sumw2_fin(Hdr* h, const float* partials) {
  if (threadIdx.x || blockIdx.x) return;
  float Sr = 0.f, Si = 0.f;
  for (int b = 0; b < 512; ++b) { Sr += partials[b * 2]; Si += partials[b * 2 + 1]; }
  float sig_r = 2.0f * sqrtf(Sr) * (1.0f / 1048576.0f);
  float sig_i = 2.0f * sqrtf(Si) * (1.0f / 1048576.0f);
  float s0 = h->amp_r / (sig_r * 1048576.0f);
  float s1 = (h->amp_i * h->amp_i) / (sig_i * 1048576.0f);
  h->scale_s[0] = s0; h->scale_s[1] = s1; h->scale_s[2] = s0; h->scale_s[3] = s1;
}

// ---- wsum -------------------------------------------------------------------
__global__ void k_wsum(const float* __restrict__ w1, const float* __restrict__ w2,
                       float2* __restrict__ wsum) {
  int idx = blockIdx.x * 256 + threadIdx.x;
  int sel = idx >> 16, rem = idx & 65535;
  const float* w = sel ? w2 : w1;
  int c = rem >> 10, m1 = (rem >> 5) & 31, m2 = rem & 31;
  size_t base = (size_t)c * 131072 + (size_t)m1 * 64 + (size_t)m2 * 2;
  float sr = 0.f, si = 0.f;
  for (int oc = 0; oc < 64; ++oc) { sr += w[base + (size_t)oc * 2048]; si += w[base + (size_t)oc * 2048 + 1]; }
  wsum[idx] = make_float2(sr, si);
}

// ---- noise spectra ----------------------------------------------------------
__global__ void k_noise_spec(float2* __restrict__ spec, const Hdr* __restrict__ h, KeyArgs ka) {
  const int combo = blockIdx.y;
  const int s = combo >> 1, part = combo & 1;
  const float nhe = ((s & 1) == 0) ? h->nhe_r : h->nhe_i;
  const uint32_t K0 = ka.k[combo][0], K1 = ka.k[combo][1];
  float2* sp = spec + (size_t)s * SPEC_STRIDE;
  const int i = blockIdx.x * 256 + threadIdx.x;
#if JPART
  if (i >= (int)NSPEC) return;
  uint32_t o0, o1; tf2x32(K0, K1, 0u, (uint32_t)i, o0, o1);
#if PART_XOR
  uint32_t bits = o0 ^ o1;
#else
  uint32_t bits = o1;
#endif
  float val = normal_from_bits(bits) * sscale_f((uint32_t)i, nhe);
  if (i == 0 || i == (int)NHALF) val = part ? 0.0f : val * 1.41421356f;
  if (part) sp[i].y = val; else sp[i].x = val;
#else
  if (i >= 262145) return;
  uint32_t c1 = (i == 262144) ? 0u : (uint32_t)(i + 262145);
  uint32_t o0, o1; tf2x32(K0, K1, (uint32_t)i, c1, o0, o1);
  {
    uint32_t k = (uint32_t)i;
    float v = normal_from_bits(o0) * sscale_f(k, nhe);
    if (k == 0u) v = part ? 0.0f : v * 1.41421356f;
    if (part) sp[k].y = v; else sp[k].x = v;
  }
  if (i < 262144) {
    uint32_t k = (uint32_t)i + 262145u;
    float v = normal_from_bits(o1) * sscale_f(k, nhe);
    if (k == NHALF) v = part ? 0.0f : v * 1.41421356f;
    if (part) sp[k].y = v; else sp[k].x = v;
  }
#endif
}

// ---- 1024-point DFT (sign +) in LDS ----------------------------------------
__device__ inline void fft1024(float2* io, float2* tmp, int t) {
  #pragma unroll
  for (int q = 0; q < 4; ++q) {
    int p = t + (q << 8); int a = p >> 5, c = p & 31;
    float2 wst = wexp((float)c * (1.0f / 32.0f));
    float2 w = wst;
    float2 sv = io[a];
    for (int b = 1; b < 32; ++b) {
      float2 v = io[a + (b << 5)];
      sv.x = fmaf(v.x, w.x, sv.x); sv.x = fmaf(-v.y, w.y, sv.x);
      sv.y = fmaf(v.x, w.y, sv.y); sv.y = fmaf(v.y, w.x, sv.y);
      w = cmul(w, wst);
    }
    float2 tw = wexp((float)(c * a) * (1.0f / 1024.0f));
    tmp[(a << 5) + c] = cmul(sv, tw);
  }
  __syncthreads();
  #pragma unroll
  for (int q = 0; q < 4; ++q) {
    int p = t + (q << 8); int d = p >> 5, c = p & 31;
    float2 wst = wexp((float)d * (1.0f / 32.0f));
    float2 w = wst;
    float2 sv = tmp[c];
    for (int a = 1; a < 32; ++a) {
      float2 v = tmp[(a << 5) + c];
      sv.x = fmaf(v.x, w.x, sv.x); sv.x = fmaf(-v.y, w.y, sv.x);
      sv.y = fmaf(v.x, w.y, sv.y); sv.y = fmaf(v.y, w.x, sv.y);
      w = cmul(w, wst);
    }
    io[c + (d << 5)] = sv;
  }
  __syncthreads();
}

__global__ __launch_bounds__(256) void k_fft_s1(const float2* __restrict__ spec,
                                                float2* __restrict__ G) {
  __shared__ float2 io[1024], tmp[1024];
  const int k1 = blockIdx.x, arr = blockIdx.y, t = threadIdx.x;
  const float2* sp = spec + (size_t)arr * SPEC_STRIDE;
  #pragma unroll
  for (int q = 0; q < 4; ++q) {
    int k2 = t + (q << 8);
    uint32_t k = (uint32_t)k1 + ((uint32_t)k2 << 10);
    float2 cv;
    if (k <= NHALF) cv = sp[k];
    else { float2 v = sp[N20 - k]; cv = make_float2(v.x, -v.y); }
    io[k2] = cv;
  }
  __syncthreads();
  fft1024(io, tmp, t);
  #pragma unroll
  for (int q = 0; q < 4; ++q) {
    int j2 = t + (q << 8);
    float2 tw = wexp((float)(j2 * k1) * (1.0f / 1048576.0f));
    float2 v = cmul(io[j2], tw);
    G[((size_t)arr << 20) + ((size_t)j2 << 10) + (size_t)k1] = v;
  }
}

__global__ __launch_bounds__(256) void k_fft_s2(const float2* __restrict__ G,
                                                float* __restrict__ noise,
                                                const Hdr* __restrict__ h) {
  __shared__ float2 io[1024], tmp[1024];
  const int j2 = blockIdx.x, arr = blockIdx.y, t = threadIdx.x;
  const float2* gp = G + ((size_t)arr << 20) + ((size_t)j2 << 10);
  #pragma unroll
  for (int q = 0; q < 4; ++q) { int k1 = t + (q << 8); io[k1] = gp[k1]; }
  __syncthreads();
  fft1024(io, tmp, t);
  const float sc = h->scale_s[arr];
  float* np_ = noise + ((size_t)arr << 20) + ((size_t)j2 << 10);
  #pragma unroll
  for (int q = 0; q < 4; ++q) { int j1 = t + (q << 8); np_[j1] = io[j1].x * sc; }
}

// ---- forward ----------------------------------------------------------------
__global__ __launch_bounds__(256, 3) void k_forward(const float* __restrict__ x,
    const float2* __restrict__ wsum, const float* __restrict__ noise,
    const Hdr* __restrict__ h, float2* __restrict__ oftg) {
  __shared__ float xs[32][257];
  __shared__ float2 X1c[32][33];
  const int bc = blockIdx.x, t = threadIdx.x;
  const int c = bc & 63;
  const int kx1 = t >> 3, yb = (t & 7) << 2;
  const int kxo = t & 31, kg = t >> 5;

  float2 acc[8];
  #pragma unroll
  for (int r = 0; r < 8; ++r) acc[r] = make_float2(0.f, 0.f);

  float2 wst1 = wexp((float)kx1 * (1.0f / 256.0f)); wst1.y = -wst1.y;
  const float* xim = x + ((size_t)bc << 16);

  for (int y0 = 0; y0 < 256; y0 += 32) {
    #pragma unroll
    for (int i = 0; i < 32; ++i) xs[i][t] = xim[(size_t)((y0 + i) << 8) + t];
    __syncthreads();
    {
      float2 s0 = make_float2(0.f,0.f), s1 = s0, s2 = s0, s3 = s0;
      float2 w = make_float2(1.f, 0.f);
      for (int xx = 0; xx < 256; ++xx) {
        float a0 = xs[yb + 0][xx], a1 = xs[yb + 1][xx], a2 = xs[yb + 2][xx], a3 = xs[yb + 3][xx];
        s0.x = fmaf(a0, w.x, s0.x); s0.y = fmaf(a0, w.y, s0.y);
        s1.x = fmaf(a1, w.x, s1.x); s1.y = fmaf(a1, w.y, s1.y);
        s2.x = fmaf(a2, w.x, s2.x); s2.y = fmaf(a2, w.y, s2.y);
        s3.x = fmaf(a3, w.x, s3.x); s3.y = fmaf(a3, w.y, s3.y);
        w = cmul(w, wst1);
      }
      X1c[yb + 0][kx1] = s0; X1c[yb + 1][kx1] = s1; X1c[yb + 2][kx1] = s2; X1c[yb + 3][kx1] = s3;
    }
    __syncthreads();
    #pragma unroll
    for (int r = 0; r < 8; ++r) {
      int kyp = (kg << 3) + r;
      int ky = (kyp < 32) ? kyp : kyp + 192;
      float2 w = wexp((float)((ky * y0) & 255) * (1.0f / 256.0f)); w.y = -w.y;
      float2 wst = wexp((float)(ky & 255) * (1.0f / 256.0f)); wst.y = -wst.y;
      float2 a = acc[r];
      for (int yy = 0; yy < 32; ++yy) {
        float2 v = X1c[yy][kxo];
        a.x = fmaf(v.x, w.x, a.x); a.x = fmaf(-v.y, w.y, a.x);
        a.y = fmaf(v.x, w.y, a.y); a.y = fmaf(v.y, w.x, a.y);
        w = cmul(w, wst);
      }
      acc[r] = a;
    }
    __syncthreads();
  }

  const int phir = h->phi_r, phii = h->phi_i;
  #pragma unroll
  for (int r = 0; r < 8; ++r) {
    int kyp = (kg << 3) + r;
    int sel = kyp >> 5;
    int m1 = kyp & 31;
    float2 wv = wsum[((size_t)sel << 16) + (size_t)(((c << 5) | m1) << 5) + (size_t)kxo];
    float2 v;
    v.x = acc[r].x * wv.x - acc[r].y * wv.y;
    v.y = acc[r].x * wv.y + acc[r].y * wv.x;
    uint32_t p = ((uint32_t)((bc << 5) | m1) << 5) | (uint32_t)kxo;
    uint32_t qr = (p - (uint32_t)phir) & (N20 - 1u);
    uint32_t qi = (p - (uint32_t)phii) & (N20 - 1u);
    const float* nr = noise + ((size_t)(sel ? 2 : 0) << 20);
    const float* ni = noise + ((size_t)(sel ? 3 : 1) << 20);
    v.x -= nr[((qr & 1023u) << 10) | (qr >> 10)];
    v.y -= ni[((qi & 1023u) << 10) | (qi >> 10)];
    oftg[((size_t)bc << 11) + (size_t)((kyp << 5) | kxo)] = v;
  }
}

// ---- inverse constants: A_E[256 y][128 p] and B2T[256 x][64 j] (bf16) -------
__global__ __launch_bounds__(256) void k_prep(unsigned short* __restrict__ A_E,
                                              unsigned short* __restrict__ B2T) {
  int t = blockIdx.x * 256 + threadIdx.x;
  if (t < 32768) {
    int y = t >> 7, p = t & 127;
    int kyp = p & 63; int ky = (kyp < 32) ? kyp : kyp + 192;
    float s, c; sincospif(2.0f * (float)((ky * y) & 255) * (1.0f / 256.0f), &s, &c);
    A_E[t] = f2bf((p < 64) ? c : s);
  } else if (t < 49152) {
    int u = t - 32768;
    int x = u >> 6, j = u & 63, kx = j & 31;
    float s, c; sincospif(2.0f * (float)((kx * x) & 255) * (1.0f / 256.0f), &s, &c);
    float v = (j < 32) ? ((kx == 0) ? 1.0f : 2.0f * c)
                       : ((kx == 0) ? 0.0f : -2.0f * s);
    B2T[u] = f2bf(v * (1.0f / 65536.0f));
  }
}

// ---- inverse via two bf16 MFMA GEMMs per image ------------------------------
// T(256x64) = A_E(256x128) . M(128x64);  out(256x256) = T . B2(64x256)
__global__ __launch_bounds__(256) void k_inverse(const float2* __restrict__ oftg,
    const unsigned short* __restrict__ A_E, const unsigned short* __restrict__ B2T,
    float* __restrict__ out) {
  __shared__ char smem[49152];
  char* Tb = smem + 16384;              // 32KB bf16 T, XOR-swizzled rows
  float* ofs = (float*)(smem + 16384);  // 16KB oft staging (dead before Tb writes)

  const int bc = blockIdx.x, t = threadIdx.x;
  const int l = t & 63, w = t >> 6, lr = l & 31, kg = l >> 5;

  // stage oft (coalesced float4)
  {
    const float4* src = (const float4*)(oftg + ((size_t)bc << 11));
    float4* dst = (float4*)ofs;
    #pragma unroll
    for (int i = 0; i < 4; ++i) dst[t + (i << 8)] = src[t + (i << 8)];
  }
  __syncthreads();

  // build Mt[64 j][128 p] (bf16, XOR-swizzled) from oft
  #pragma unroll
  for (int i = 0; i < 32; ++i) {
    int idx = t + (i << 8);
    int p = idx >> 6, j = idx & 63;
    int kyp = p & 63;
    float v;
    if (p < 64) v = (j < 32) ? ofs[(kyp << 6) + (j << 1)]
                             : ofs[(kyp << 6) + ((j - 32) << 1) + 1];
    else        v = (j < 32) ? -ofs[(kyp << 6) + (j << 1) + 1]
                             : ofs[(kyp << 6) + ((j - 32) << 1)];
    int byte = ((j << 8) + (p << 1)) ^ ((j & 7) << 4);
    *(unsigned short*)(smem + byte) = f2bf(v);
  }
  __syncthreads();

  // GEMM1: acc[rt][ct] over K=128 (8 steps of 16)
  f32x16 acc[2][2];
  acc[0][0] = zero16(); acc[0][1] = zero16(); acc[1][0] = zero16(); acc[1][1] = zero16();
  #pragma unroll
  for (int s = 0; s < 8; ++s) {
    short8 af[2], bf[2];
    #pragma unroll
    for (int rt = 0; rt < 2; ++rt) {
      int row = (w << 6) + (rt << 5) + lr;
      af[rt] = *(const short8*)(A_E + (row << 7) + (s << 4) + (kg << 3));
    }
    #pragma unroll
    for (int ct = 0; ct < 2; ++ct) {
      int j = (ct << 5) + lr;
      int byte = ((j << 8) + (s << 5) + (kg << 4)) ^ ((j & 7) << 4);
      bf[ct] = *(const short8*)(smem + byte);
    }
    #pragma unroll
    for (int rt = 0; rt < 2; ++rt)
      #pragma unroll
      for (int ct = 0; ct < 2; ++ct)
        acc[rt][ct] = __builtin_amdgcn_mfma_f32_32x32x16_bf16(af[rt], bf[ct], acc[rt][ct], 0, 0, 0);
  }

  // write T rows as bf16, swizzled
  #pragma unroll
  for (int rt = 0; rt < 2; ++rt)
    #pragma unroll
    for (int ct = 0; ct < 2; ++ct)
      #pragma unroll
      for (int r = 0; r < 16; ++r) {
        int row = (w << 6) + (rt << 5) + (r & 3) + (((r >> 2) & 3) << 3) + (kg << 2);
        int col = (ct << 5) + lr;
        int byte = ((row << 7) + (col << 1)) ^ ((row & 7) << 4);
        *(unsigned short*)(Tb + byte) = f2bf(acc[rt][ct][r]);
      }
  __syncthreads();

  // GEMM2: out = T(256x64) . B2(64x256); A-frags hoisted
  short8 ta[2][4];
  #pragma unroll
  for (int rt = 0; rt < 2; ++rt)
    #pragma unroll
    for (int ks = 0; ks < 4; ++ks) {
      int row = (w << 6) + (rt << 5) + lr;
      int byte = ((row << 7) + (ks << 5) + (kg << 4)) ^ ((row & 7) << 4);
      ta[rt][ks] = *(const short8*)(Tb + byte);
    }
  float* op = out + ((size_t)bc << 16);
  #pragma unroll
  for (int cc = 0; cc < 4; ++cc) {
    short8 b2[2][4];
    #pragma unroll
    for (int cx = 0; cx < 2; ++cx)
      #pragma unroll
      for (int ks = 0; ks < 4; ++ks) {
        int xx = (cc << 6) + (cx << 5) + lr;
        b2[cx][ks] = *(const short8*)(B2T + (xx << 6) + (ks << 4) + (kg << 3));
      }
    f32x16 a2[2][2];
    a2[0][0] = zero16(); a2[0][1] = zero16(); a2[1][0] = zero16(); a2[1][1] = zero16();
    #pragma unroll
    for (int ks = 0; ks < 4; ++ks)
      #pragma unroll
      for (int rt = 0; rt < 2; ++rt)
        #pragma unroll
        for (int cx = 0; cx < 2; ++cx)
          a2[rt][cx] = __builtin_amdgcn_mfma_f32_32x32x16_bf16(ta[rt][ks], b2[cx][ks], a2[rt][cx], 0, 0, 0);
    #pragma unroll
    for (int rt = 0; rt < 2; ++rt)
      #pragma unroll
      for (int cx = 0; cx < 2; ++cx)
        #pragma unroll
        for (int r = 0; r < 16; ++r) {
          int row = (w << 6) + (rt << 5) + (r & 3) + (((r >> 2) & 3) << 3) + (kg << 2);
          int xx = (cc << 6) + (cx << 5) + lr;
          op[(row << 8) + xx] = a2[rt][cx][r];
        }
  }
}

// ---- host -------------------------------------------------------------------
extern "C" void kernel_launch(void* const* d_in, const int* in_sizes, int n_in,
                              void* d_out, int out_size, void* d_ws, size_t ws_size,
                              hipStream_t stream) {
  (void)in_sizes; (void)n_in; (void)out_size; (void)ws_size;
  const float* x   = (const float*)d_in[0];
  const float* w1  = (const float*)d_in[1];
  const float* w2  = (const float*)d_in[2];
  const float* er  = (const float*)d_in[3];
  const float* ei  = (const float*)d_in[4];
  const float* ar  = (const float*)d_in[5];
  const float* ai  = (const float*)d_in[6];
  const float* pr  = (const float*)d_in[7];
  const float* pim = (const float*)d_in[8];
  float* out = (float*)d_out;

  char* ws = (char*)d_ws;
  Hdr*    hdr      = (Hdr*)ws;
  float*  partials = (float*)(ws + 0x1000);
  float2* wsum     = (float2*)(ws + 0x10000);
  unsigned short* A_E = (unsigned short*)(ws + 0x130000);  // 64KB
  unsigned short* B2T = (unsigned short*)(ws + 0x140000);  // 32KB
  float2* spec     = (float2*)(ws + 0x200000);
  float2* G        = (float2*)(ws + 0x1400000);
  float2* oft      = (float2*)(ws + 0x1400000);
  float*  noise    = (float*)(ws + 0x3400000);

  auto splitk = [](const uint32_t k[2], uint32_t a[2], uint32_t b[2]) {
#if JPART
    tf2x32(k[0], k[1], 0u, 0u, a[0], a[1]);
    tf2x32(k[0], k[1], 0u, 1u, b[0], b[1]);
#else
    uint32_t r0[2], r1[2];
    tf2x32(k[0], k[1], 0u, 2u, r0[0], r0[1]);
    tf2x32(k[0], k[1], 1u, 3u, r1[0], r1[1]);
    a[0] = r0[0]; a[1] = r1[0]; b[0] = r0[1]; b[1] = r1[1];
#endif
  };
  uint32_t root[2] = { 0u, 42u };
  uint32_t kA[2], kB[2], k1A[2], k2A[2], k1B[2], k2B[2];
  splitk(root, kA, kB);
  splitk(kA, k1A, k2A);
  splitk(kB, k1B, k2B);
  KeyArgs ka;
  splitk(k1A, ka.k[0], ka.k[1]);
  splitk(k2A, ka.k[2], ka.k[3]);
  splitk(k1B, ka.k[4], ka.k[5]);
  splitk(k2B, ka.k[6], ka.k[7]);

  hipLaunchKernelGGL(k_scalars,    dim3(1),        dim3(64),  0, stream, hdr, er, ei, ar, ai, pr, pim);
  hipLaunchKernelGGL(k_sumw2,      dim3(512),      dim3(256), 0, stream, hdr, partials);
  hipLaunchKernelGGL(k_sumw2_fin,  dim3(1),        dim3(64),  0, stream, hdr, partials);
  hipLaunchKernelGGL(k_wsum,       dim3(512),      dim3(256), 0, stream, w1, w2, wsum);
  hipLaunchKernelGGL(k_prep,       dim3(192),      dim3(256), 0, stream, A_E, B2T);
  hipLaunchKernelGGL(k_noise_spec, dim3(2049, 8),  dim3(256), 0, stream, spec, hdr, ka);
  hipLaunchKernelGGL(k_fft_s1,     dim3(1024, 4),  dim3(256), 0, stream, spec, G);
  hipLaunchKernelGGL(k_fft_s2,     dim3(1024, 4),  dim3(256), 0, stream, G, noise, hdr);
  hipLaunchKernelGGL(k_forward,    dim3(1024),     dim3(256), 0, stream, x, wsum, noise, hdr, oft);
  hipLaunchKernelGGL(k_inverse,    dim3(1024),     dim3(256), 0, stream, oft, A_E, B2T, out);
}

// Round 4
// 570.281 us; speedup vs baseline: 3.0656x; 1.6003x over previous
//
#include <hip/hip_runtime.h>
#include <cstdint>

// ---- JAX PRNG mode switches -------------------------------------------------
#define JPART 1
#define PART_XOR 1

constexpr uint32_t N20   = 1u << 20;
constexpr uint32_t NHALF = 1u << 19;
constexpr uint32_t NSPEC = NHALF + 1;
constexpr uint32_t SPEC_STRIDE = 524544;

struct Hdr {
  float e_r, e_i, amp_r, amp_i;
  int   phi_r, phi_i;
  float nhe_r, nhe_i;
  float scale_s[4];
};
struct KeyArgs { uint32_t k[8][2]; };

typedef __attribute__((ext_vector_type(8))) short short8;
typedef __attribute__((ext_vector_type(16))) float f32x16;

__device__ inline f32x16 zero16() {
  f32x16 v;
  #pragma unroll
  for (int i = 0; i < 16; ++i) v[i] = 0.f;
  return v;
}

__device__ inline unsigned short f2bf(float f) {
  uint32_t u = __float_as_uint(f);
  return (unsigned short)((u + 0x7fffu + ((u >> 16) & 1u)) >> 16);
}

// ---- Threefry2x32-20 (exact JAX cipher) ------------------------------------
__host__ __device__ inline void tf2x32(uint32_t k0, uint32_t k1, uint32_t x0, uint32_t x1,
                                       uint32_t& o0, uint32_t& o1) {
  const uint32_t ks0 = k0, ks1 = k1, ks2 = k0 ^ k1 ^ 0x1BD11BDAu;
  const uint32_t ks[3] = { ks0, ks1, ks2 };
  x0 += ks0; x1 += ks1;
  const int rot[2][4] = { {13,15,26,6}, {17,29,16,24} };
  for (int g = 0; g < 5; ++g) {
    const int* rr = rot[g & 1];
    for (int i = 0; i < 4; ++i) {
      x0 += x1;
      x1 = (x1 << rr[i]) | (x1 >> (32 - rr[i]));
      x1 ^= x0;
    }
    x0 += ks[(g + 1) % 3];
    x1 += ks[(g + 2) % 3] + (uint32_t)(g + 1);
  }
  o0 = x0; o1 = x1;
}

// ---- XLA ErfInv32 polynomial ------------------------------------------------
__device__ inline float erfinv_xla(float x) {
  float w = -log1pf(-x * x);
  float p;
  if (w < 5.0f) {
    w -= 2.5f;
    p = 2.81022636e-08f;
    p = fmaf(p, w, 3.43273939e-07f);
    p = fmaf(p, w, -3.5233877e-06f);
    p = fmaf(p, w, -4.39150654e-06f);
    p = fmaf(p, w, 0.00021858087f);
    p = fmaf(p, w, -0.00125372503f);
    p = fmaf(p, w, -0.00417768164f);
    p = fmaf(p, w, 0.246640727f);
    p = fmaf(p, w, 1.50140941f);
  } else {
    w = sqrtf(w) - 3.0f;
    p = -0.000200214257f;
    p = fmaf(p, w, 0.000100950558f);
    p = fmaf(p, w, 0.00134934322f);
    p = fmaf(p, w, -0.00367342844f);
    p = fmaf(p, w, 0.00573950773f);
    p = fmaf(p, w, -0.0076224613f);
    p = fmaf(p, w, 0.00943887047f);
    p = fmaf(p, w, 1.00167406f);
    p = fmaf(p, w, 2.83297682f);
  }
  return p * x;
}

__device__ inline float normal_from_bits(uint32_t bits) {
  uint32_t fb = (bits >> 9) | 0x3f800000u;
  float f = __uint_as_float(fb) - 1.0f;
  const float LO = -0.99999994f;
  float u = f * 2.0f + LO;
  u = fmaxf(LO, u);
  return 1.41421356f * erfinv_xla(u);
}

__device__ inline float sscale_f(uint32_t k, float nhe) {
  uint32_t kk = k ? k : 1u;
  return powf((float)kk * (1.0f / 1048576.0f), nhe);
}

__device__ inline float2 cmul(float2 a, float2 b) {
  return make_float2(a.x * b.x - a.y * b.y, a.x * b.y + a.y * b.x);
}
__device__ inline float2 wexp(float u) {
  float s, c; sincospif(2.0f * u, &s, &c); return make_float2(c, s);
}

// ---- scalars ----------------------------------------------------------------
__device__ inline float med8_dev(const float* p) {
  float v[8];
  for (int i = 0; i < 8; ++i) v[i] = p[i];
  for (int i = 1; i < 8; ++i) { float key = v[i]; int j = i - 1;
    while (j >= 0 && v[j] > key) { v[j + 1] = v[j]; --j; } v[j + 1] = key; }
  return 0.5f * (v[3] + v[4]);
}

__global__ void k_scalars(Hdr* h, const float* er, const float* ei, const float* ar,
                          const float* ai, const float* pr, const float* pim) {
  if (threadIdx.x || blockIdx.x) return;
  float mer = med8_dev(er), mei = med8_dev(ei);
  h->e_r = mer; h->e_i = mei;
  h->amp_r = med8_dev(ar); h->amp_i = med8_dev(ai);
  h->phi_r = (int)med8_dev(pr);
  h->phi_i = (int)med8_dev(pim);
  h->nhe_r = -0.5f * mer; h->nhe_i = -0.5f * mei;
}

__global__ void k_sumw2(const Hdr* __restrict__ h, float* __restrict__ partials) {
  __shared__ float sr_[256], si_[256];
  const float nher = h->nhe_r, nhei = h->nhe_i;
  float sr = 0.f, si = 0.f;
  for (int j = 0; j < 4; ++j) {
    uint32_t k = (uint32_t)(blockIdx.x * 1024 + j * 256 + threadIdx.x) + 1u;
    float fk = (float)k * (1.0f / 1048576.0f);
    float wr = powf(fk, nher), wi = powf(fk, nhei);
    if (k == NHALF) { wr *= 0.5f; wi *= 0.5f; }
    sr += wr * wr; si += wi * wi;
  }
  sr_[threadIdx.x] = sr; si_[threadIdx.x] = si; __syncthreads();
  for (int off = 128; off > 0; off >>= 1) {
    if ((int)threadIdx.x < off) { sr_[threadIdx.x] += sr_[threadIdx.x + off];
                                  si_[threadIdx.x] += si_[threadIdx.x + off]; }
    __syncthreads();
  }
  if (!threadIdx.x) { partials[blockIdx.x * 2] = sr_[0]; partials[blockIdx.x * 2 + 1] = si_[0]; }
}

__global__ void k_sumw2_fin(Hdr* h, const float* partials) {
  if (threadIdx.x || blockIdx.x) return;
  float Sr = 0.f, Si = 0.f;
  for (int b = 0; b < 512; ++b) { Sr += partials[b * 2]; Si += partials[b * 2 + 1]; }
  float sig_r = 2.0f * sqrtf(Sr) * (1.0f / 1048576.0f);
  float sig_i = 2.0f * sqrtf(Si) * (1.0f / 1048576.0f);
  float s0 = h->amp_r / (sig_r * 1048576.0f);
  float s1 = (h->amp_i * h->amp_i) / (sig_i * 1048576.0f);
  h->scale_s[0] = s0; h->scale_s[1] = s1; h->scale_s[2] = s0; h->scale_s[3] = s1;
}

// ---- wsum -------------------------------------------------------------------
__global__ void k_wsum(const float* __restrict__ w1, const float* __restrict__ w2,
                       float2* __restrict__ wsum) {
  int idx = blockIdx.x * 256 + threadIdx.x;
  int sel = idx >> 16, rem = idx & 65535;
  const float* w = sel ? w2 : w1;
  int c = rem >> 10, m1 = (rem >> 5) & 31, m2 = rem & 31;
  size_t base = (size_t)c * 131072 + (size_t)m1 * 64 + (size_t)m2 * 2;
  float sr = 0.f, si = 0.f;
  for (int oc = 0; oc < 64; ++oc) { sr += w[base + (size_t)oc * 2048]; si += w[base + (size_t)oc * 2048 + 1]; }
  wsum[idx] = make_float2(sr, si);
}

// ---- noise spectra ----------------------------------------------------------
__global__ void k_noise_spec(float2* __restrict__ spec, const Hdr* __restrict__ h, KeyArgs ka) {
  const int combo = blockIdx.y;
  const int s = combo >> 1, part = combo & 1;
  const float nhe = ((s & 1) == 0) ? h->nhe_r : h->nhe_i;
  const uint32_t K0 = ka.k[combo][0], K1 = ka.k[combo][1];
  float2* sp = spec + (size_t)s * SPEC_STRIDE;
  const int i = blockIdx.x * 256 + threadIdx.x;
#if JPART
  if (i >= (int)NSPEC) return;
  uint32_t o0, o1; tf2x32(K0, K1, 0u, (uint32_t)i, o0, o1);
#if PART_XOR
  uint32_t bits = o0 ^ o1;
#else
  uint32_t bits = o1;
#endif
  float val = normal_from_bits(bits) * sscale_f((uint32_t)i, nhe);
  if (i == 0 || i == (int)NHALF) val = part ? 0.0f : val * 1.41421356f;
  if (part) sp[i].y = val; else sp[i].x = val;
#else
  if (i >= 262145) return;
  uint32_t c1 = (i == 262144) ? 0u : (uint32_t)(i + 262145);
  uint32_t o0, o1; tf2x32(K0, K1, (uint32_t)i, c1, o0, o1);
  {
    uint32_t k = (uint32_t)i;
    float v = normal_from_bits(o0) * sscale_f(k, nhe);
    if (k == 0u) v = part ? 0.0f : v * 1.41421356f;
    if (part) sp[k].y = v; else sp[k].x = v;
  }
  if (i < 262144) {
    uint32_t k = (uint32_t)i + 262145u;
    float v = normal_from_bits(o1) * sscale_f(k, nhe);
    if (k == NHALF) v = part ? 0.0f : v * 1.41421356f;
    if (part) sp[k].y = v; else sp[k].x = v;
  }
#endif
}

// ---- 1024-point DFT (sign +) in LDS ----------------------------------------
__device__ inline void fft1024(float2* io, float2* tmp, int t) {
  #pragma unroll
  for (int q = 0; q < 4; ++q) {
    int p = t + (q << 8); int a = p >> 5, c = p & 31;
    float2 wst = wexp((float)c * (1.0f / 32.0f));
    float2 w = wst;
    float2 sv = io[a];
    for (int b = 1; b < 32; ++b) {
      float2 v = io[a + (b << 5)];
      sv.x = fmaf(v.x, w.x, sv.x); sv.x = fmaf(-v.y, w.y, sv.x);
      sv.y = fmaf(v.x, w.y, sv.y); sv.y = fmaf(v.y, w.x, sv.y);
      w = cmul(w, wst);
    }
    float2 tw = wexp((float)(c * a) * (1.0f / 1024.0f));
    tmp[(a << 5) + c] = cmul(sv, tw);
  }
  __syncthreads();
  #pragma unroll
  for (int q = 0; q < 4; ++q) {
    int p = t + (q << 8); int d = p >> 5, c = p & 31;
    float2 wst = wexp((float)d * (1.0f / 32.0f));
    float2 w = wst;
    float2 sv = tmp[c];
    for (int a = 1; a < 32; ++a) {
      float2 v = tmp[(a << 5) + c];
      sv.x = fmaf(v.x, w.x, sv.x); sv.x = fmaf(-v.y, w.y, sv.x);
      sv.y = fmaf(v.x, w.y, sv.y); sv.y = fmaf(v.y, w.x, sv.y);
      w = cmul(w, wst);
    }
    io[c + (d << 5)] = sv;
  }
  __syncthreads();
}

__global__ __launch_bounds__(256) void k_fft_s1(const float2* __restrict__ spec,
                                                float2* __restrict__ G) {
  __shared__ float2 io[1024], tmp[1024];
  const int k1 = blockIdx.x, arr = blockIdx.y, t = threadIdx.x;
  const float2* sp = spec + (size_t)arr * SPEC_STRIDE;
  #pragma unroll
  for (int q = 0; q < 4; ++q) {
    int k2 = t + (q << 8);
    uint32_t k = (uint32_t)k1 + ((uint32_t)k2 << 10);
    float2 cv;
    if (k <= NHALF) cv = sp[k];
    else { float2 v = sp[N20 - k]; cv = make_float2(v.x, -v.y); }
    io[k2] = cv;
  }
  __syncthreads();
  fft1024(io, tmp, t);
  #pragma unroll
  for (int q = 0; q < 4; ++q) {
    int j2 = t + (q << 8);
    float2 tw = wexp((float)(j2 * k1) * (1.0f / 1048576.0f));
    float2 v = cmul(io[j2], tw);
    G[((size_t)arr << 20) + ((size_t)j2 << 10) + (size_t)k1] = v;
  }
}

__global__ __launch_bounds__(256) void k_fft_s2(const float2* __restrict__ G,
                                                float* __restrict__ noise,
                                                const Hdr* __restrict__ h) {
  __shared__ float2 io[1024], tmp[1024];
  const int j2 = blockIdx.x, arr = blockIdx.y, t = threadIdx.x;
  const float2* gp = G + ((size_t)arr << 20) + ((size_t)j2 << 10);
  #pragma unroll
  for (int q = 0; q < 4; ++q) { int k1 = t + (q << 8); io[k1] = gp[k1]; }
  __syncthreads();
  fft1024(io, tmp, t);
  const float sc = h->scale_s[arr];
  float* np_ = noise + ((size_t)arr << 20) + ((size_t)j2 << 10);
  #pragma unroll
  for (int q = 0; q < 4; ++q) { int j1 = t + (q << 8); np_[j1] = io[j1].x * sc; }
}

// ---- constants: A_E, B2T (inverse) + ET, Fc, Fs, Fns (forward) --------------
__global__ __launch_bounds__(256) void k_prep(unsigned short* __restrict__ A_E,
                                              unsigned short* __restrict__ B2T,
                                              unsigned short* __restrict__ ET,
                                              unsigned short* __restrict__ Fc,
                                              unsigned short* __restrict__ Fs,
                                              unsigned short* __restrict__ Fns) {
  int t = blockIdx.x * 256 + threadIdx.x;
  if (t < 32768) {
    int y = t >> 7, p = t & 127;
    int kyp = p & 63; int ky = (kyp < 32) ? kyp : kyp + 192;
    float s, c; sincospif(2.0f * (float)((ky * y) & 255) * (1.0f / 256.0f), &s, &c);
    A_E[t] = f2bf((p < 64) ? c : s);
  } else if (t < 49152) {
    int u = t - 32768;
    int x = u >> 6, j = u & 63, kx = j & 31;
    float s, c; sincospif(2.0f * (float)((kx * x) & 255) * (1.0f / 256.0f), &s, &c);
    float v = (j < 32) ? ((kx == 0) ? 1.0f : 2.0f * c)
                       : ((kx == 0) ? 0.0f : -2.0f * s);
    B2T[u] = f2bf(v * (1.0f / 65536.0f));
  } else if (t < 65536) {
    int u = t - 49152;                      // ET[col 64][xx 256]
    int col = u >> 8, xx = u & 255; int kx = col & 31;
    float s, c; sincospif(2.0f * (float)((kx * xx) & 255) * (1.0f / 256.0f), &s, &c);
    ET[u] = f2bf((col < 32) ? c : -s);
  } else if (t < 114688) {
    int u = (t - 65536) & 16383;            // F*[kyp 64][y 256]
    int which = (t - 65536) >> 14;          // 0:Fc 1:Fs 2:Fns
    int kyp = u >> 8, y = u & 255; int ky = (kyp < 32) ? kyp : kyp + 192;
    float s, c; sincospif(2.0f * (float)((ky * y) & 255) * (1.0f / 256.0f), &s, &c);
    if (which == 0) Fc[u] = f2bf(c);
    else if (which == 1) Fs[u] = f2bf(s);
    else Fns[u] = f2bf(-s);
  }
}

// ---- forward via MFMA --------------------------------------------------------
// Stage1: X1(256y x [Re32|Im32]) = x(256x256)*ET^T; stored transposed X1T[col][y]
// Stage2: O_re = Fc.X1re + Fs.X1im ; O_im = Fc.X1im + Fns.X1re  (K = 256 y)
__global__ __launch_bounds__(256) void k_forward(const float* __restrict__ x,
    const float2* __restrict__ wsum, const float* __restrict__ noise,
    const Hdr* __restrict__ h,
    const unsigned short* __restrict__ ET, const unsigned short* __restrict__ Fc,
    const unsigned short* __restrict__ Fs, const unsigned short* __restrict__ Fns,
    float2* __restrict__ oftg) {
  __shared__ char lds[65536];
  char* X1T = lds + 32768;                    // [64 col][256 y] bf16, swizzled
  const int bc = blockIdx.x, t = threadIdx.x;
  const int c = bc & 63;
  const int l = t & 63, w = t >> 6, lr = l & 31, kg = l >> 5;
  const int rt = w >> 1, ct = w & 1;
  const float* xim = x + ((size_t)bc << 16);

  // ---- stage 1: 4 y-tiles of 64 rows
  for (int yt = 0; yt < 4; ++yt) {
    __syncthreads();
    #pragma unroll
    for (int i = 0; i < 16; ++i) {
      int f4 = i * 256 + t;
      int r = f4 >> 6, c4 = f4 & 63;
      float4 v = *(const float4*)(xim + (size_t)(((yt << 6) + r) << 8) + (c4 << 2));
      ushort4 b4; b4.x = f2bf(v.x); b4.y = f2bf(v.y); b4.z = f2bf(v.z); b4.w = f2bf(v.w);
      int byte = ((r << 9) + (c4 << 3)) ^ ((r & 7) << 4);
      *(ushort4*)(lds + byte) = b4;
    }
    __syncthreads();
    f32x16 a1 = zero16();
    const int arow = (rt << 5) + lr;
    const int bcol = (ct << 5) + lr;
    #pragma unroll
    for (int s = 0; s < 16; ++s) {
      short8 af = *(const short8*)(lds + (((arow << 9) + (s << 5) + (kg << 4)) ^ ((arow & 7) << 4)));
      short8 bf = *(const short8*)(ET + (bcol << 8) + (s << 4) + (kg << 3));
      a1 = __builtin_amdgcn_mfma_f32_32x32x16_bf16(af, bf, a1, 0, 0, 0);
    }
    #pragma unroll
    for (int r4 = 0; r4 < 4; ++r4) {
      int y0 = (yt << 6) + (rt << 5) + (r4 << 3) + (kg << 2);
      ushort4 p4;
      p4.x = f2bf(a1[r4 * 4 + 0]); p4.y = f2bf(a1[r4 * 4 + 1]);
      p4.z = f2bf(a1[r4 * 4 + 2]); p4.w = f2bf(a1[r4 * 4 + 3]);
      int byte = ((bcol << 9) + (y0 << 1)) ^ ((bcol & 7) << 4);
      *(ushort4*)(X1T + byte) = p4;
    }
  }
  __syncthreads();

  // ---- stage 2
  const int re_im = w >> 1, kt = w & 1;
  const unsigned short* A1p = re_im ? Fns : Fs;
  const int b0row = (re_im ? 32 : 0) + lr;    // paired with Fc
  const int b1row = (re_im ? 0 : 32) + lr;    // paired with Fs/Fns
  const int a2row = (kt << 5) + lr;
  f32x16 a2 = zero16();
  #pragma unroll
  for (int s = 0; s < 16; ++s) {
    short8 a0f = *(const short8*)(Fc  + (a2row << 8) + (s << 4) + (kg << 3));
    short8 a1f = *(const short8*)(A1p + (a2row << 8) + (s << 4) + (kg << 3));
    short8 b0f = *(const short8*)(X1T + (((b0row << 9) + (s << 5) + (kg << 4)) ^ ((b0row & 7) << 4)));
    short8 b1f = *(const short8*)(X1T + (((b1row << 9) + (s << 5) + (kg << 4)) ^ ((b1row & 7) << 4)));
    a2 = __builtin_amdgcn_mfma_f32_32x32x16_bf16(a0f, b0f, a2, 0, 0, 0);
    a2 = __builtin_amdgcn_mfma_f32_32x32x16_bf16(a1f, b1f, a2, 0, 0, 0);
  }
  float* Osm = (float*)(lds + (re_im << 13)); // re @0, im @8192 ([64 kyp][32 kx] f32)
  #pragma unroll
  for (int i = 0; i < 16; ++i) {
    int row = (kt << 5) + (i & 3) + ((i >> 2) << 3) + (kg << 2);
    Osm[(row << 5) + lr] = a2[i];
  }
  __syncthreads();

  // ---- epilogue: wsum mul + noise subtract
  const int phir = h->phi_r, phii = h->phi_i;
  const float* Ore = (const float*)lds;
  const float* Oim = (const float*)(lds + 8192);
  #pragma unroll
  for (int r = 0; r < 8; ++r) {
    int idx = (r << 8) + t;
    int kyp = idx >> 5, kx = idx & 31;
    int sel = kyp >> 5, m1 = kyp & 31;
    float2 av = make_float2(Ore[idx], Oim[idx]);
    float2 wv = wsum[((size_t)sel << 16) + (size_t)(((c << 5) | m1) << 5) + (size_t)kx];
    float2 v;
    v.x = av.x * wv.x - av.y * wv.y;
    v.y = av.x * wv.y + av.y * wv.x;
    uint32_t p = ((uint32_t)((bc << 5) | m1) << 5) | (uint32_t)kx;
    uint32_t qr = (p - (uint32_t)phir) & (N20 - 1u);
    uint32_t qi = (p - (uint32_t)phii) & (N20 - 1u);
    const float* nr = noise + ((size_t)(sel ? 2 : 0) << 20);
    const float* ni = noise + ((size_t)(sel ? 3 : 1) << 20);
    v.x -= nr[((qr & 1023u) << 10) | (qr >> 10)];
    v.y -= ni[((qi & 1023u) << 10) | (qi >> 10)];
    oftg[((size_t)bc << 11) + (size_t)idx] = v;
  }
}

// ---- inverse via two bf16 MFMA GEMMs per image ------------------------------
__global__ __launch_bounds__(256) void k_inverse(const float2* __restrict__ oftg,
    const unsigned short* __restrict__ A_E, const unsigned short* __restrict__ B2T,
    float* __restrict__ out) {
  __shared__ char smem[49152];
  char* Tb = smem + 16384;
  float* ofs = (float*)(smem + 16384);

  const int bc = blockIdx.x, t = threadIdx.x;
  const int l = t & 63, w = t >> 6, lr = l & 31, kg = l >> 5;

  {
    const float4* src = (const float4*)(oftg + ((size_t)bc << 11));
    float4* dst = (float4*)ofs;
    #pragma unroll
    for (int i = 0; i < 4; ++i) dst[t + (i << 8)] = src[t + (i << 8)];
  }
  __syncthreads();

  #pragma unroll
  for (int i = 0; i < 32; ++i) {
    int idx = t + (i << 8);
    int p = idx >> 6, j = idx & 63;
    int kyp = p & 63;
    float v;
    if (p < 64) v = (j < 32) ? ofs[(kyp << 6) + (j << 1)]
                             : ofs[(kyp << 6) + ((j - 32) << 1) + 1];
    else        v = (j < 32) ? -ofs[(kyp << 6) + (j << 1) + 1]
                             : ofs[(kyp << 6) + ((j - 32) << 1)];
    int byte = ((j << 8) + (p << 1)) ^ ((j & 7) << 4);
    *(unsigned short*)(smem + byte) = f2bf(v);
  }
  __syncthreads();

  f32x16 acc[2][2];
  acc[0][0] = zero16(); acc[0][1] = zero16(); acc[1][0] = zero16(); acc[1][1] = zero16();
  #pragma unroll
  for (int s = 0; s < 8; ++s) {
    short8 af[2], bf[2];
    #pragma unroll
    for (int rt = 0; rt < 2; ++rt) {
      int row = (w << 6) + (rt << 5) + lr;
      af[rt] = *(const short8*)(A_E + (row << 7) + (s << 4) + (kg << 3));
    }
    #pragma unroll
    for (int ct = 0; ct < 2; ++ct) {
      int j = (ct << 5) + lr;
      int byte = ((j << 8) + (s << 5) + (kg << 4)) ^ ((j & 7) << 4);
      bf[ct] = *(const short8*)(smem + byte);
    }
    #pragma unroll
    for (int rt = 0; rt < 2; ++rt)
      #pragma unroll
      for (int ct = 0; ct < 2; ++ct)
        acc[rt][ct] = __builtin_amdgcn_mfma_f32_32x32x16_bf16(af[rt], bf[ct], acc[rt][ct], 0, 0, 0);
  }

  #pragma unroll
  for (int rt = 0; rt < 2; ++rt)
    #pragma unroll
    for (int ct = 0; ct < 2; ++ct)
      #pragma unroll
      for (int r = 0; r < 16; ++r) {
        int row = (w << 6) + (rt << 5) + (r & 3) + (((r >> 2) & 3) << 3) + (kg << 2);
        int col = (ct << 5) + lr;
        int byte = ((row << 7) + (col << 1)) ^ ((row & 7) << 4);
        *(unsigned short*)(Tb + byte) = f2bf(acc[rt][ct][r]);
      }
  __syncthreads();

  short8 ta[2][4];
  #pragma unroll
  for (int rt = 0; rt < 2; ++rt)
    #pragma unroll
    for (int ks = 0; ks < 4; ++ks) {
      int row = (w << 6) + (rt << 5) + lr;
      int byte = ((row << 7) + (ks << 5) + (kg << 4)) ^ ((row & 7) << 4);
      ta[rt][ks] = *(const short8*)(Tb + byte);
    }
  float* op = out + ((size_t)bc << 16);
  #pragma unroll
  for (int cc = 0; cc < 4; ++cc) {
    short8 b2[2][4];
    #pragma unroll
    for (int cx = 0; cx < 2; ++cx)
      #pragma unroll
      for (int ks = 0; ks < 4; ++ks) {
        int xx = (cc << 6) + (cx << 5) + lr;
        b2[cx][ks] = *(const short8*)(B2T + (xx << 6) + (ks << 4) + (kg << 3));
      }
    f32x16 a2[2][2];
    a2[0][0] = zero16(); a2[0][1] = zero16(); a2[1][0] = zero16(); a2[1][1] = zero16();
    #pragma unroll
    for (int ks = 0; ks < 4; ++ks)
      #pragma unroll
      for (int rt = 0; rt < 2; ++rt)
        #pragma unroll
        for (int cx = 0; cx < 2; ++cx)
          a2[rt][cx] = __builtin_amdgcn_mfma_f32_32x32x16_bf16(ta[rt][ks], b2[cx][ks], a2[rt][cx], 0, 0, 0);
    #pragma unroll
    for (int rt = 0; rt < 2; ++rt)
      #pragma unroll
      for (int cx = 0; cx < 2; ++cx)
        #pragma unroll
        for (int r = 0; r < 16; ++r) {
          int row = (w << 6) + (rt << 5) + (r & 3) + (((r >> 2) & 3) << 3) + (kg << 2);
          int xx = (cc << 6) + (cx << 5) + lr;
          op[(row << 8) + xx] = a2[rt][cx][r];
        }
  }
}

// ---- host -------------------------------------------------------------------
extern "C" void kernel_launch(void* const* d_in, const int* in_sizes, int n_in,
                              void* d_out, int out_size, void* d_ws, size_t ws_size,
                              hipStream_t stream) {
  (void)in_sizes; (void)n_in; (void)out_size; (void)ws_size;
  const float* x   = (const float*)d_in[0];
  const float* w1  = (const float*)d_in[1];
  const float* w2  = (const float*)d_in[2];
  const float* er  = (const float*)d_in[3];
  const float* ei  = (const float*)d_in[4];
  const float* ar  = (const float*)d_in[5];
  const float* ai  = (const float*)d_in[6];
  const float* pr  = (const float*)d_in[7];
  const float* pim = (const float*)d_in[8];
  float* out = (float*)d_out;

  char* ws = (char*)d_ws;
  Hdr*    hdr      = (Hdr*)ws;
  float*  partials = (float*)(ws + 0x1000);
  float2* wsum     = (float2*)(ws + 0x10000);
  unsigned short* A_E = (unsigned short*)(ws + 0x130000);  // 64KB
  unsigned short* B2T = (unsigned short*)(ws + 0x140000);  // 32KB
  unsigned short* ET  = (unsigned short*)(ws + 0x148000);  // 32KB
  unsigned short* Fc  = (unsigned short*)(ws + 0x150000);  // 32KB
  unsigned short* Fs  = (unsigned short*)(ws + 0x158000);  // 32KB
  unsigned short* Fns = (unsigned short*)(ws + 0x160000);  // 32KB
  float2* spec     = (float2*)(ws + 0x200000);
  float2* G        = (float2*)(ws + 0x1400000);
  float2* oft      = (float2*)(ws + 0x1400000);
  float*  noise    = (float*)(ws + 0x3400000);

  auto splitk = [](const uint32_t k[2], uint32_t a[2], uint32_t b[2]) {
#if JPART
    tf2x32(k[0], k[1], 0u, 0u, a[0], a[1]);
    tf2x32(k[0], k[1], 0u, 1u, b[0], b[1]);
#else
    uint32_t r0[2], r1[2];
    tf2x32(k[0], k[1], 0u, 2u, r0[0], r0[1]);
    tf2x32(k[0], k[1], 1u, 3u, r1[0], r1[1]);
    a[0] = r0[0]; a[1] = r1[0]; b[0] = r0[1]; b[1] = r1[1];
#endif
  };
  uint32_t root[2] = { 0u, 42u };
  uint32_t kA[2], kB[2], k1A[2], k2A[2], k1B[2], k2B[2];
  splitk(root, kA, kB);
  splitk(kA, k1A, k2A);
  splitk(kB, k1B, k2B);
  KeyArgs ka;
  splitk(k1A, ka.k[0], ka.k[1]);
  splitk(k2A, ka.k[2], ka.k[3]);
  splitk(k1B, ka.k[4], ka.k[5]);
  splitk(k2B, ka.k[6], ka.k[7]);

  hipLaunchKernelGGL(k_scalars,    dim3(1),        dim3(64),  0, stream, hdr, er, ei, ar, ai, pr, pim);
  hipLaunchKernelGGL(k_sumw2,      dim3(512),      dim3(256), 0, stream, hdr, partials);
  hipLaunchKernelGGL(k_sumw2_fin,  dim3(1),        dim3(64),  0, stream, hdr, partials);
  hipLaunchKernelGGL(k_wsum,       dim3(512),      dim3(256), 0, stream, w1, w2, wsum);
  hipLaunchKernelGGL(k_prep,       dim3(448),      dim3(256), 0, stream, A_E, B2T, ET, Fc, Fs, Fns);
  hipLaunchKernelGGL(k_noise_spec, dim3(2049, 8),  dim3(256), 0, stream, spec, hdr, ka);
  hipLaunchKernelGGL(k_fft_s1,     dim3(1024, 4),  dim3(256), 0, stream, spec, G);
  hipLaunchKernelGGL(k_fft_s2,     dim3(1024, 4),  dim3(256), 0, stream, G, noise, hdr);
  hipLaunchKernelGGL(k_forward,    dim3(1024),     dim3(256), 0, stream, x, wsum, noise, hdr, ET, Fc, Fs, Fns, oft);
  hipLaunchKernelGGL(k_inverse,    dim3(1024),     dim3(256), 0, stream, oft, A_E, B2T, out);
}

// Round 5
// 321.372 us; speedup vs baseline: 5.4400x; 1.7745x over previous
//
#include <hip/hip_runtime.h>
#include <cstdint>

// ---- JAX PRNG mode switches -------------------------------------------------
#define JPART 1
#define PART_XOR 1

constexpr uint32_t N20   = 1u << 20;
constexpr uint32_t NHALF = 1u << 19;
constexpr uint32_t NSPEC = NHALF + 1;
constexpr uint32_t SPEC_STRIDE = 524544;

struct Hdr {
  float e_r, e_i, amp_r, amp_i;
  int   phi_r, phi_i;
  float nhe_r, nhe_i;
  float scale_s[4];
};
struct KeyArgs { uint32_t k[8][2]; };

typedef __attribute__((ext_vector_type(8))) short short8;
typedef __attribute__((ext_vector_type(16))) float f32x16;

__device__ inline f32x16 zero16() {
  f32x16 v;
  #pragma unroll
  for (int i = 0; i < 16; ++i) v[i] = 0.f;
  return v;
}

__device__ inline unsigned short f2bf(float f) {
  uint32_t u = __float_as_uint(f);
  return (unsigned short)((u + 0x7fffu + ((u >> 16) & 1u)) >> 16);
}

// ---- Threefry2x32-20 (exact JAX cipher) ------------------------------------
__host__ __device__ inline void tf2x32(uint32_t k0, uint32_t k1, uint32_t x0, uint32_t x1,
                                       uint32_t& o0, uint32_t& o1) {
  const uint32_t ks0 = k0, ks1 = k1, ks2 = k0 ^ k1 ^ 0x1BD11BDAu;
  const uint32_t ks[3] = { ks0, ks1, ks2 };
  x0 += ks0; x1 += ks1;
  const int rot[2][4] = { {13,15,26,6}, {17,29,16,24} };
  for (int g = 0; g < 5; ++g) {
    const int* rr = rot[g & 1];
    for (int i = 0; i < 4; ++i) {
      x0 += x1;
      x1 = (x1 << rr[i]) | (x1 >> (32 - rr[i]));
      x1 ^= x0;
    }
    x0 += ks[(g + 1) % 3];
    x1 += ks[(g + 2) % 3] + (uint32_t)(g + 1);
  }
  o0 = x0; o1 = x1;
}

// ---- XLA ErfInv32 polynomial ------------------------------------------------
__device__ inline float erfinv_xla(float x) {
  float w = -log1pf(-x * x);
  float p;
  if (w < 5.0f) {
    w -= 2.5f;
    p = 2.81022636e-08f;
    p = fmaf(p, w, 3.43273939e-07f);
    p = fmaf(p, w, -3.5233877e-06f);
    p = fmaf(p, w, -4.39150654e-06f);
    p = fmaf(p, w, 0.00021858087f);
    p = fmaf(p, w, -0.00125372503f);
    p = fmaf(p, w, -0.00417768164f);
    p = fmaf(p, w, 0.246640727f);
    p = fmaf(p, w, 1.50140941f);
  } else {
    w = sqrtf(w) - 3.0f;
    p = -0.000200214257f;
    p = fmaf(p, w, 0.000100950558f);
    p = fmaf(p, w, 0.00134934322f);
    p = fmaf(p, w, -0.00367342844f);
    p = fmaf(p, w, 0.00573950773f);
    p = fmaf(p, w, -0.0076224613f);
    p = fmaf(p, w, 0.00943887047f);
    p = fmaf(p, w, 1.00167406f);
    p = fmaf(p, w, 2.83297682f);
  }
  return p * x;
}

__device__ inline float normal_from_bits(uint32_t bits) {
  uint32_t fb = (bits >> 9) | 0x3f800000u;
  float f = __uint_as_float(fb) - 1.0f;
  const float LO = -0.99999994f;
  float u = f * 2.0f + LO;
  u = fmaxf(LO, u);
  return 1.41421356f * erfinv_xla(u);
}

__device__ inline float sscale_f(uint32_t k, float nhe) {
  uint32_t kk = k ? k : 1u;
  return powf((float)kk * (1.0f / 1048576.0f), nhe);
}

__device__ inline float2 cmul(float2 a, float2 b) {
  return make_float2(a.x * b.x - a.y * b.y, a.x * b.y + a.y * b.x);
}
__device__ inline float2 wexp(float u) {
  float s, c; sincospif(2.0f * u, &s, &c); return make_float2(c, s);
}
__device__ inline float2 cadd(float2 a, float2 b){ return make_float2(a.x+b.x, a.y+b.y); }
__device__ inline float2 csub(float2 a, float2 b){ return make_float2(a.x-b.x, a.y-b.y); }
__device__ inline float2 cmuli(float2 a){ return make_float2(-a.y, a.x); }  // * (+i)

// LDS index swizzle: bijective, keeps 16-windows intact (consecutive runs
// conflict-free), spreads stride-4/16 write patterns to <=4-way.
__device__ inline int sw(int i) { return i ^ (((i >> 4) & 3) << 2); }

// ---- scalars ----------------------------------------------------------------
__device__ inline float med8_dev(const float* p) {
  float v[8];
  for (int i = 0; i < 8; ++i) v[i] = p[i];
  for (int i = 1; i < 8; ++i) { float key = v[i]; int j = i - 1;
    while (j >= 0 && v[j] > key) { v[j + 1] = v[j]; --j; } v[j + 1] = key; }
  return 0.5f * (v[3] + v[4]);
}

__global__ void k_scalars(Hdr* h, const float* er, const float* ei, const float* ar,
                          const float* ai, const float* pr, const float* pim) {
  if (threadIdx.x || blockIdx.x) return;
  float mer = med8_dev(er), mei = med8_dev(ei);
  h->e_r = mer; h->e_i = mei;
  h->amp_r = med8_dev(ar); h->amp_i = med8_dev(ai);
  h->phi_r = (int)med8_dev(pr);
  h->phi_i = (int)med8_dev(pim);
  h->nhe_r = -0.5f * mer; h->nhe_i = -0.5f * mei;
}

__global__ void k_sumw2(const Hdr* __restrict__ h, float* __restrict__ partials) {
  __shared__ float sr_[256], si_[256];
  const float nher = h->nhe_r, nhei = h->nhe_i;
  float sr = 0.f, si = 0.f;
  for (int j = 0; j < 4; ++j) {
    uint32_t k = (uint32_t)(blockIdx.x * 1024 + j * 256 + threadIdx.x) + 1u;
    float fk = (float)k * (1.0f / 1048576.0f);
    float wr = powf(fk, nher), wi = powf(fk, nhei);
    if (k == NHALF) { wr *= 0.5f; wi *= 0.5f; }
    sr += wr * wr; si += wi * wi;
  }
  sr_[threadIdx.x] = sr; si_[threadIdx.x] = si; __syncthreads();
  for (int off = 128; off > 0; off >>= 1) {
    if ((int)threadIdx.x < off) { sr_[threadIdx.x] += sr_[threadIdx.x + off];
                                  si_[threadIdx.x] += si_[threadIdx.x + off]; }
    __syncthreads();
  }
  if (!threadIdx.x) { partials[blockIdx.x * 2] = sr_[0]; partials[blockIdx.x * 2 + 1] = si_[0]; }
}

__global__ void k_sumw2_fin(Hdr* h, const float* partials) {
  if (threadIdx.x || blockIdx.x) return;
  float Sr = 0.f, Si = 0.f;
  for (int b = 0; b < 512; ++b) { Sr += partials[b * 2]; Si += partials[b * 2 + 1]; }
  float sig_r = 2.0f * sqrtf(Sr) * (1.0f / 1048576.0f);
  float sig_i = 2.0f * sqrtf(Si) * (1.0f / 1048576.0f);
  float s0 = h->amp_r / (sig_r * 1048576.0f);
  float s1 = (h->amp_i * h->amp_i) / (sig_i * 1048576.0f);
  h->scale_s[0] = s0; h->scale_s[1] = s1; h->scale_s[2] = s0; h->scale_s[3] = s1;
}

// ---- wsum -------------------------------------------------------------------
__global__ void k_wsum(const float* __restrict__ w1, const float* __restrict__ w2,
                       float2* __restrict__ wsum) {
  int idx = blockIdx.x * 256 + threadIdx.x;
  int sel = idx >> 16, rem = idx & 65535;
  const float* w = sel ? w2 : w1;
  int c = rem >> 10, m1 = (rem >> 5) & 31, m2 = rem & 31;
  size_t base = (size_t)c * 131072 + (size_t)m1 * 64 + (size_t)m2 * 2;
  float sr = 0.f, si = 0.f;
  for (int oc = 0; oc < 64; ++oc) { sr += w[base + (size_t)oc * 2048]; si += w[base + (size_t)oc * 2048 + 1]; }
  wsum[idx] = make_float2(sr, si);
}

// ---- noise spectra ----------------------------------------------------------
__global__ void k_noise_spec(float2* __restrict__ spec, const Hdr* __restrict__ h, KeyArgs ka) {
  const int combo = blockIdx.y;
  const int s = combo >> 1, part = combo & 1;
  const float nhe = ((s & 1) == 0) ? h->nhe_r : h->nhe_i;
  const uint32_t K0 = ka.k[combo][0], K1 = ka.k[combo][1];
  float2* sp = spec + (size_t)s * SPEC_STRIDE;
  const int i = blockIdx.x * 256 + threadIdx.x;
#if JPART
  if (i >= (int)NSPEC) return;
  uint32_t o0, o1; tf2x32(K0, K1, 0u, (uint32_t)i, o0, o1);
#if PART_XOR
  uint32_t bits = o0 ^ o1;
#else
  uint32_t bits = o1;
#endif
  float val = normal_from_bits(bits) * sscale_f((uint32_t)i, nhe);
  if (i == 0 || i == (int)NHALF) val = part ? 0.0f : val * 1.41421356f;
  if (part) sp[i].y = val; else sp[i].x = val;
#else
  if (i >= 262145) return;
  uint32_t c1 = (i == 262144) ? 0u : (uint32_t)(i + 262145);
  uint32_t o0, o1; tf2x32(K0, K1, (uint32_t)i, c1, o0, o1);
  {
    uint32_t k = (uint32_t)i;
    float v = normal_from_bits(o0) * sscale_f(k, nhe);
    if (k == 0u) v = part ? 0.0f : v * 1.41421356f;
    if (part) sp[k].y = v; else sp[k].x = v;
  }
  if (i < 262144) {
    uint32_t k = (uint32_t)i + 262145u;
    float v = normal_from_bits(o1) * sscale_f(k, nhe);
    if (k == NHALF) v = part ? 0.0f : v * 1.41421356f;
    if (part) sp[k].y = v; else sp[k].x = v;
  }
#endif
}

// ---- radix-4 Stockham 1024-pt FFT (sign +), LDS ping-pong, 5 stages ---------
template<int L, int M>
__device__ inline void r4_stage(const float2* __restrict__ src, float2* __restrict__ dst, int t) {
  const int j = t / M;
  const int k = t % M;
  float2 c0 = src[sw(t)];
  float2 c1 = src[sw(t + 256)];
  float2 c2 = src[sw(t + 512)];
  float2 c3 = src[sw(t + 768)];
  float2 d0 = cadd(c0, c2), d1 = csub(c0, c2);
  float2 d2 = cadd(c1, c3), d3 = cmuli(csub(c1, c3));
  float2 w1 = wexp((float)j * (1.0f / (float)(4 * L)));
  float2 w2 = cmul(w1, w1);
  float2 w3 = cmul(w2, w1);
  int base = k + 4 * j * M;
  dst[sw(base)]         = cadd(d0, d2);
  dst[sw(base + M)]     = cmul(w1, cadd(d1, d3));
  dst[sw(base + 2 * M)] = cmul(w2, csub(d0, d2));
  dst[sw(base + 3 * M)] = cmul(w3, csub(d1, d3));
}

// input in A (sw-indexed), result in B (sw-indexed)
__device__ inline void fft1024_r4(float2* A, float2* B, int t) {
  __syncthreads();
  r4_stage<256, 1>(A, B, t);   __syncthreads();
  r4_stage<64, 4>(B, A, t);    __syncthreads();
  r4_stage<16, 16>(A, B, t);   __syncthreads();
  r4_stage<4, 64>(B, A, t);    __syncthreads();
  r4_stage<1, 256>(A, B, t);   __syncthreads();
}

// ---- irfft(2^20) stage 1: per k1, FFT over k2; G[k1][j2] coalesced ----------
__global__ __launch_bounds__(256) void k_fft_s1(const float2* __restrict__ spec,
                                                float2* __restrict__ G) {
  __shared__ float2 A[1024], B[1024];
  const int sid = blockIdx.x;
  const int lin = (sid & 7) * 512 + (sid >> 3);     // XCD-chunked (4096%8==0)
  const int arr = lin >> 10, k1 = lin & 1023;
  const int t = threadIdx.x;
  const float2* sp = spec + (size_t)arr * SPEC_STRIDE;
  #pragma unroll
  for (int q = 0; q < 4; ++q) {
    int k2 = t + (q << 8);
    uint32_t k = (uint32_t)k1 + ((uint32_t)k2 << 10);
    float2 cv;
    if (k <= NHALF) cv = sp[k];
    else { float2 v = sp[N20 - k]; cv = make_float2(v.x, -v.y); }
    A[sw(k2)] = cv;
  }
  fft1024_r4(A, B, t);
  float2* gp = G + ((size_t)arr << 20) + ((size_t)k1 << 10);
  #pragma unroll
  for (int q = 0; q < 4; ++q) {
    int j2 = t + (q << 8);
    float2 tw = wexp((float)(j2 * k1) * (1.0f / 1048576.0f));
    gp[j2] = cmul(B[sw(j2)], tw);
  }
}

// ---- stage 2: per j2, FFT over k1 (strided reads, L2-clustered) -------------
__global__ __launch_bounds__(256) void k_fft_s2(const float2* __restrict__ G,
                                                float* __restrict__ noise,
                                                const Hdr* __restrict__ h) {
  __shared__ float2 A[1024], B[1024];
  const int sid = blockIdx.x;
  const int lin = (sid & 7) * 512 + (sid >> 3);
  const int arr = lin >> 10, j2 = lin & 1023;
  const int t = threadIdx.x;
  const float2* gp = G + ((size_t)arr << 20) + (size_t)j2;
  #pragma unroll
  for (int q = 0; q < 4; ++q) {
    int k1 = t + (q << 8);
    A[sw(k1)] = gp[(size_t)k1 << 10];
  }
  fft1024_r4(A, B, t);
  const float sc = h->scale_s[arr];
  float* np_ = noise + ((size_t)arr << 20) + ((size_t)j2 << 10);
  #pragma unroll
  for (int q = 0; q < 4; ++q) { int j1 = t + (q << 8); np_[j1] = B[sw(j1)].x * sc; }
}

// ---- constants: A_E, B2T (inverse) + ET, Fc, Fs, Fns (forward) --------------
__global__ __launch_bounds__(256) void k_prep(unsigned short* __restrict__ A_E,
                                              unsigned short* __restrict__ B2T,
                                              unsigned short* __restrict__ ET,
                                              unsigned short* __restrict__ Fc,
                                              unsigned short* __restrict__ Fs,
                                              unsigned short* __restrict__ Fns) {
  int t = blockIdx.x * 256 + threadIdx.x;
  if (t < 32768) {
    int y = t >> 7, p = t & 127;
    int kyp = p & 63; int ky = (kyp < 32) ? kyp : kyp + 192;
    float s, c; sincospif(2.0f * (float)((ky * y) & 255) * (1.0f / 256.0f), &s, &c);
    A_E[t] = f2bf((p < 64) ? c : s);
  } else if (t < 49152) {
    int u = t - 32768;
    int x = u >> 6, j = u & 63, kx = j & 31;
    float s, c; sincospif(2.0f * (float)((kx * x) & 255) * (1.0f / 256.0f), &s, &c);
    float v = (j < 32) ? ((kx == 0) ? 1.0f : 2.0f * c)
                       : ((kx == 0) ? 0.0f : -2.0f * s);
    B2T[u] = f2bf(v * (1.0f / 65536.0f));
  } else if (t < 65536) {
    int u = t - 49152;                      // ET[col 64][xx 256]
    int col = u >> 8, xx = u & 255; int kx = col & 31;
    float s, c; sincospif(2.0f * (float)((kx * xx) & 255) * (1.0f / 256.0f), &s, &c);
    ET[u] = f2bf((col < 32) ? c : -s);
  } else if (t < 114688) {
    int u = (t - 65536) & 16383;            // F*[kyp 64][y 256]
    int which = (t - 65536) >> 14;          // 0:Fc 1:Fs 2:Fns
    int kyp = u >> 8, y = u & 255; int ky = (kyp < 32) ? kyp : kyp + 192;
    float s, c; sincospif(2.0f * (float)((ky * y) & 255) * (1.0f / 256.0f), &s, &c);
    if (which == 0) Fc[u] = f2bf(c);
    else if (which == 1) Fs[u] = f2bf(s);
    else Fns[u] = f2bf(-s);
  }
}

// ---- forward via MFMA --------------------------------------------------------
__global__ __launch_bounds__(256) void k_forward(const float* __restrict__ x,
    const float2* __restrict__ wsum, const float* __restrict__ noise,
    const Hdr* __restrict__ h,
    const unsigned short* __restrict__ ET, const unsigned short* __restrict__ Fc,
    const unsigned short* __restrict__ Fs, const unsigned short* __restrict__ Fns,
    float2* __restrict__ oftg) {
  __shared__ char lds[65536];
  char* X1T = lds + 32768;                    // [64 col][256 y] bf16, swizzled
  const int bc = blockIdx.x, t = threadIdx.x;
  const int c = bc & 63;
  const int l = t & 63, w = t >> 6, lr = l & 31, kg = l >> 5;
  const int rt = w >> 1, ct = w & 1;
  const float* xim = x + ((size_t)bc << 16);

  for (int yt = 0; yt < 4; ++yt) {
    __syncthreads();
    #pragma unroll
    for (int i = 0; i < 16; ++i) {
      int f4 = i * 256 + t;
      int r = f4 >> 6, c4 = f4 & 63;
      float4 v = *(const float4*)(xim + (size_t)(((yt << 6) + r) << 8) + (c4 << 2));
      ushort4 b4; b4.x = f2bf(v.x); b4.y = f2bf(v.y); b4.z = f2bf(v.z); b4.w = f2bf(v.w);
      int byte = ((r << 9) + (c4 << 3)) ^ ((r & 7) << 4);
      *(ushort4*)(lds + byte) = b4;
    }
    __syncthreads();
    f32x16 a1 = zero16();
    const int arow = (rt << 5) + lr;
    const int bcol = (ct << 5) + lr;
    #pragma unroll
    for (int s = 0; s < 16; ++s) {
      short8 af = *(const short8*)(lds + (((arow << 9) + (s << 5) + (kg << 4)) ^ ((arow & 7) << 4)));
      short8 bf = *(const short8*)(ET + (bcol << 8) + (s << 4) + (kg << 3));
      a1 = __builtin_amdgcn_mfma_f32_32x32x16_bf16(af, bf, a1, 0, 0, 0);
    }
    #pragma unroll
    for (int r4 = 0; r4 < 4; ++r4) {
      int y0 = (yt << 6) + (rt << 5) + (r4 << 3) + (kg << 2);
      ushort4 p4;
      p4.x = f2bf(a1[r4 * 4 + 0]); p4.y = f2bf(a1[r4 * 4 + 1]);
      p4.z = f2bf(a1[r4 * 4 + 2]); p4.w = f2bf(a1[r4 * 4 + 3]);
      int byte = ((bcol << 9) + (y0 << 1)) ^ ((bcol & 7) << 4);
      *(ushort4*)(X1T + byte) = p4;
    }
  }
  __syncthreads();

  const int re_im = w >> 1, kt = w & 1;
  const unsigned short* A1p = re_im ? Fns : Fs;
  const int b0row = (re_im ? 32 : 0) + lr;
  const int b1row = (re_im ? 0 : 32) + lr;
  const int a2row = (kt << 5) + lr;
  f32x16 a2 = zero16();
  #pragma unroll
  for (int s = 0; s < 16; ++s) {
    short8 a0f = *(const short8*)(Fc  + (a2row << 8) + (s << 4) + (kg << 3));
    short8 a1f = *(const short8*)(A1p + (a2row << 8) + (s << 4) + (kg << 3));
    short8 b0f = *(const short8*)(X1T + (((b0row << 9) + (s << 5) + (kg << 4)) ^ ((b0row & 7) << 4)));
    short8 b1f = *(const short8*)(X1T + (((b1row << 9) + (s << 5) + (kg << 4)) ^ ((b1row & 7) << 4)));
    a2 = __builtin_amdgcn_mfma_f32_32x32x16_bf16(a0f, b0f, a2, 0, 0, 0);
    a2 = __builtin_amdgcn_mfma_f32_32x32x16_bf16(a1f, b1f, a2, 0, 0, 0);
  }
  float* Osm = (float*)(lds + (re_im << 13));
  #pragma unroll
  for (int i = 0; i < 16; ++i) {
    int row = (kt << 5) + (i & 3) + ((i >> 2) << 3) + (kg << 2);
    Osm[(row << 5) + lr] = a2[i];
  }
  __syncthreads();

  const int phir = h->phi_r, phii = h->phi_i;
  const float* Ore = (const float*)lds;
  const float* Oim = (const float*)(lds + 8192);
  #pragma unroll
  for (int r = 0; r < 8; ++r) {
    int idx = (r << 8) + t;
    int kyp = idx >> 5, kx = idx & 31;
    int sel = kyp >> 5, m1 = kyp & 31;
    float2 av = make_float2(Ore[idx], Oim[idx]);
    float2 wv = wsum[((size_t)sel << 16) + (size_t)(((c << 5) | m1) << 5) + (size_t)kx];
    float2 v;
    v.x = av.x * wv.x - av.y * wv.y;
    v.y = av.x * wv.y + av.y * wv.x;
    uint32_t p = ((uint32_t)((bc << 5) | m1) << 5) | (uint32_t)kx;
    uint32_t qr = (p - (uint32_t)phir) & (N20 - 1u);
    uint32_t qi = (p - (uint32_t)phii) & (N20 - 1u);
    const float* nr = noise + ((size_t)(sel ? 2 : 0) << 20);
    const float* ni = noise + ((size_t)(sel ? 3 : 1) << 20);
    v.x -= nr[((qr & 1023u) << 10) | (qr >> 10)];
    v.y -= ni[((qi & 1023u) << 10) | (qi >> 10)];
    oftg[((size_t)bc << 11) + (size_t)idx] = v;
  }
}

// ---- inverse via two bf16 MFMA GEMMs per image ------------------------------
__global__ __launch_bounds__(256) void k_inverse(const float2* __restrict__ oftg,
    const unsigned short* __restrict__ A_E, const unsigned short* __restrict__ B2T,
    float* __restrict__ out) {
  __shared__ char smem[49152];
  char* Tb = smem + 16384;
  float* ofs = (float*)(smem + 16384);

  const int bc = blockIdx.x, t = threadIdx.x;
  const int l = t & 63, w = t >> 6, lr = l & 31, kg = l >> 5;

  {
    const float4* src = (const float4*)(oftg + ((size_t)bc << 11));
    float4* dst = (float4*)ofs;
    #pragma unroll
    for (int i = 0; i < 4; ++i) dst[t + (i << 8)] = src[t + (i << 8)];
  }
  __syncthreads();

  #pragma unroll
  for (int i = 0; i < 32; ++i) {
    int idx = t + (i << 8);
    int p = idx >> 6, j = idx & 63;
    int kyp = p & 63;
    float v;
    if (p < 64) v = (j < 32) ? ofs[(kyp << 6) + (j << 1)]
                             : ofs[(kyp << 6) + ((j - 32) << 1) + 1];
    else        v = (j < 32) ? -ofs[(kyp << 6) + (j << 1) + 1]
                             : ofs[(kyp << 6) + ((j - 32) << 1)];
    int byte = ((j << 8) + (p << 1)) ^ ((j & 7) << 4);
    *(unsigned short*)(smem + byte) = f2bf(v);
  }
  __syncthreads();

  f32x16 acc[2][2];
  acc[0][0] = zero16(); acc[0][1] = zero16(); acc[1][0] = zero16(); acc[1][1] = zero16();
  #pragma unroll
  for (int s = 0; s < 8; ++s) {
    short8 af[2], bf[2];
    #pragma unroll
    for (int rt = 0; rt < 2; ++rt) {
      int row = (w << 6) + (rt << 5) + lr;
      af[rt] = *(const short8*)(A_E + (row << 7) + (s << 4) + (kg << 3));
    }
    #pragma unroll
    for (int ct = 0; ct < 2; ++ct) {
      int j = (ct << 5) + lr;
      int byte = ((j << 8) + (s << 5) + (kg << 4)) ^ ((j & 7) << 4);
      bf[ct] = *(const short8*)(smem + byte);
    }
    #pragma unroll
    for (int rt = 0; rt < 2; ++rt)
      #pragma unroll
      for (int ct = 0; ct < 2; ++ct)
        acc[rt][ct] = __builtin_amdgcn_mfma_f32_32x32x16_bf16(af[rt], bf[ct], acc[rt][ct], 0, 0, 0);
  }

  #pragma unroll
  for (int rt = 0; rt < 2; ++rt)
    #pragma unroll
    for (int ct = 0; ct < 2; ++ct)
      #pragma unroll
      for (int r = 0; r < 16; ++r) {
        int row = (w << 6) + (rt << 5) + (r & 3) + (((r >> 2) & 3) << 3) + (kg << 2);
        int col = (ct << 5) + lr;
        int byte = ((row << 7) + (col << 1)) ^ ((row & 7) << 4);
        *(unsigned short*)(Tb + byte) = f2bf(acc[rt][ct][r]);
      }
  __syncthreads();

  short8 ta[2][4];
  #pragma unroll
  for (int rt = 0; rt < 2; ++rt)
    #pragma unroll
    for (int ks = 0; ks < 4; ++ks) {
      int row = (w << 6) + (rt << 5) + lr;
      int byte = ((row << 7) + (ks << 5) + (kg << 4)) ^ ((row & 7) << 4);
      ta[rt][ks] = *(const short8*)(Tb + byte);
    }
  float* op = out + ((size_t)bc << 16);
  #pragma unroll
  for (int cc = 0; cc < 4; ++cc) {
    short8 b2[2][4];
    #pragma unroll
    for (int cx = 0; cx < 2; ++cx)
      #pragma unroll
      for (int ks = 0; ks < 4; ++ks) {
        int xx = (cc << 6) + (cx << 5) + lr;
        b2[cx][ks] = *(const short8*)(B2T + (xx << 6) + (ks << 4) + (kg << 3));
      }
    f32x16 a2[2][2];
    a2[0][0] = zero16(); a2[0][1] = zero16(); a2[1][0] = zero16(); a2[1][1] = zero16();
    #pragma unroll
    for (int ks = 0; ks < 4; ++ks)
      #pragma unroll
      for (int rt = 0; rt < 2; ++rt)
        #pragma unroll
        for (int cx = 0; cx < 2; ++cx)
          a2[rt][cx] = __builtin_amdgcn_mfma_f32_32x32x16_bf16(ta[rt][ks], b2[cx][ks], a2[rt][cx], 0, 0, 0);
    #pragma unroll
    for (int rt = 0; rt < 2; ++rt)
      #pragma unroll
      for (int cx = 0; cx < 2; ++cx)
        #pragma unroll
        for (int r = 0; r < 16; ++r) {
          int row = (w << 6) + (rt << 5) + (r & 3) + (((r >> 2) & 3) << 3) + (kg << 2);
          int xx = (cc << 6) + (cx << 5) + lr;
          op[(row << 8) + xx] = a2[rt][cx][r];
        }
  }
}

// ---- host -------------------------------------------------------------------
extern "C" void kernel_launch(void* const* d_in, const int* in_sizes, int n_in,
                              void* d_out, int out_size, void* d_ws, size_t ws_size,
                              hipStream_t stream) {
  (void)in_sizes; (void)n_in; (void)out_size; (void)ws_size;
  const float* x   = (const float*)d_in[0];
  const float* w1  = (const float*)d_in[1];
  const float* w2  = (const float*)d_in[2];
  const float* er  = (const float*)d_in[3];
  const float* ei  = (const float*)d_in[4];
  const float* ar  = (const float*)d_in[5];
  const float* ai  = (const float*)d_in[6];
  const float* pr  = (const float*)d_in[7];
  const float* pim = (const float*)d_in[8];
  float* out = (float*)d_out;

  char* ws = (char*)d_ws;
  Hdr*    hdr      = (Hdr*)ws;
  float*  partials = (float*)(ws + 0x1000);
  float2* wsum     = (float2*)(ws + 0x10000);
  unsigned short* A_E = (unsigned short*)(ws + 0x130000);
  unsigned short* B2T = (unsigned short*)(ws + 0x140000);
  unsigned short* ET  = (unsigned short*)(ws + 0x148000);
  unsigned short* Fc  = (unsigned short*)(ws + 0x150000);
  unsigned short* Fs  = (unsigned short*)(ws + 0x158000);
  unsigned short* Fns = (unsigned short*)(ws + 0x160000);
  float2* spec     = (float2*)(ws + 0x200000);
  float2* G        = (float2*)(ws + 0x1400000);
  float2* oft      = (float2*)(ws + 0x1400000);
  float*  noise    = (float*)(ws + 0x3400000);

  auto splitk = [](const uint32_t k[2], uint32_t a[2], uint32_t b[2]) {
#if JPART
    tf2x32(k[0], k[1], 0u, 0u, a[0], a[1]);
    tf2x32(k[0], k[1], 0u, 1u, b[0], b[1]);
#else
    uint32_t r0[2], r1[2];
    tf2x32(k[0], k[1], 0u, 2u, r0[0], r0[1]);
    tf2x32(k[0], k[1], 1u, 3u, r1[0], r1[1]);
    a[0] = r0[0]; a[1] = r1[0]; b[0] = r0[1]; b[1] = r1[1];
#endif
  };
  uint32_t root[2] = { 0u, 42u };
  uint32_t kA[2], kB[2], k1A[2], k2A[2], k1B[2], k2B[2];
  splitk(root, kA, kB);
  splitk(kA, k1A, k2A);
  splitk(kB, k1B, k2B);
  KeyArgs ka;
  splitk(k1A, ka.k[0], ka.k[1]);
  splitk(k2A, ka.k[2], ka.k[3]);
  splitk(k1B, ka.k[4], ka.k[5]);
  splitk(k2B, ka.k[6], ka.k[7]);

  hipLaunchKernelGGL(k_scalars,    dim3(1),        dim3(64),  0, stream, hdr, er, ei, ar, ai, pr, pim);
  hipLaunchKernelGGL(k_sumw2,      dim3(512),      dim3(256), 0, stream, hdr, partials);
  hipLaunchKernelGGL(k_sumw2_fin,  dim3(1),        dim3(64),  0, stream, hdr, partials);
  hipLaunchKernelGGL(k_wsum,       dim3(512),      dim3(256), 0, stream, w1, w2, wsum);
  hipLaunchKernelGGL(k_prep,       dim3(448),      dim3(256), 0, stream, A_E, B2T, ET, Fc, Fs, Fns);
  hipLaunchKernelGGL(k_noise_spec, dim3(2049, 8),  dim3(256), 0, stream, spec, hdr, ka);
  hipLaunchKernelGGL(k_fft_s1,     dim3(4096),     dim3(256), 0, stream, spec, G);
  hipLaunchKernelGGL(k_fft_s2,     dim3(4096),     dim3(256), 0, stream, G, noise, hdr);
  hipLaunchKernelGGL(k_forward,    dim3(1024),     dim3(256), 0, stream, x, wsum, noise, hdr, ET, Fc, Fs, Fns, oft);
  hipLaunchKernelGGL(k_inverse,    dim3(1024),     dim3(256), 0, stream, oft, A_E, B2T, out);
}